// Round 6
// baseline (719.064 us; speedup 1.0000x reference)
//
#include <hip/hip_runtime.h>

typedef __bf16 bf16x8 __attribute__((ext_vector_type(8)));
typedef __bf16 bf16x4 __attribute__((ext_vector_type(4)));
typedef float f32x4 __attribute__((ext_vector_type(4)));
typedef unsigned short us8 __attribute__((ext_vector_type(8)));
typedef unsigned short us4 __attribute__((ext_vector_type(4)));
typedef short sh4 __attribute__((ext_vector_type(4)));

#define SCALE_Q 0.17677669529663687f  // 32^-0.5

__device__ __forceinline__ unsigned short f2b(float f) {
    __bf16 h = (__bf16)f;                       // RNE, packs to v_cvt_pk_bf16_f32
    return __builtin_bit_cast(unsigned short, h);
}
__device__ __forceinline__ float b2f(unsigned short h) {
    union { unsigned u; float f; } v; v.u = ((unsigned)h) << 16;
    return v.f;
}
__device__ __forceinline__ f32x4 mfma16(us8 a, us8 b, f32x4 c) {
    return __builtin_amdgcn_mfma_f32_16x16x32_bf16(
        __builtin_bit_cast(bf16x8, a), __builtin_bit_cast(bf16x8, b), c, 0, 0, 0);
}

// K=16 bf16 MFMA. A/B frag: 4 bf16, elem k=(lane>>4)*4+j. C/D standard.
#if __has_builtin(__builtin_amdgcn_mfma_f32_16x16x16bf16_1k)
__device__ __forceinline__ f32x4 mfma16k16(us4 a, us4 b, f32x4 c) {
    return __builtin_amdgcn_mfma_f32_16x16x16bf16_1k(
        __builtin_bit_cast(sh4, a), __builtin_bit_cast(sh4, b), c, 0, 0, 0);
}
#elif __has_builtin(__builtin_amdgcn_mfma_f32_16x16x16_bf16)
__device__ __forceinline__ f32x4 mfma16k16(us4 a, us4 b, f32x4 c) {
    return __builtin_amdgcn_mfma_f32_16x16x16_bf16(
        __builtin_bit_cast(bf16x4, a), __builtin_bit_cast(bf16x4, b), c, 0, 0, 0);
}
#else
__device__ __forceinline__ f32x4 mfma16k16(us4 a, us4 b, f32x4 c) {
    asm volatile("v_mfma_f32_16x16x16_bf16 %0, %1, %2, %0"
                 : "+v"(c) : "v"(a), "v"(b));
    return c;
}
#endif

__device__ __forceinline__ us8 lds_ld8(const unsigned short* base, int byteoff) {
    return *(const us8*)((const char*)base + byteoff);
}
__device__ __forceinline__ void lds_st8(unsigned short* base, int byteoff, us8 v) {
    *(us8*)((char*)base + byteoff) = v;
}

// ---------- weight transpose + bf16 convert:  dst[c][r] = src[r][c] ----------
__global__ void k_transpose(const float* __restrict__ src, unsigned short* __restrict__ dst,
                            int R, int C) {
    int idx = blockIdx.x * 256 + threadIdx.x;
    if (idx >= R * C) return;
    int r = idx / C, c = idx - r * C;
    dst[c * R + r] = f2b(src[idx]);
}

// ---------- pack MLP weights into per-ct 8KB fragment slices ----------
__global__ void k_pack_mlp(const float* __restrict__ fc1_w, const float* __restrict__ fc2_w,
                           unsigned short* __restrict__ wPack) {
    int gid = blockIdx.x * 256 + threadIdx.x;          // 131072 shorts total
    int ct = gid >> 12;                                 // 4096 shorts / slice
    int byte = (gid & 4095) * 2;
    float v;
    if (byte < 4096) {
        int kk = byte >> 10, rem = byte & 1023;
        int lane = rem >> 4, j = (rem & 15) >> 1;
        v = fc1_w[(size_t)(kk * 32 + (lane >> 4) * 8 + j) * 512 + ct * 16 + (lane & 15)];
    } else {
        int b2 = byte - 4096;
        int co = b2 >> 9, rem = b2 & 511;
        int lane = rem >> 3, j = (rem & 7) >> 1;
        v = fc2_w[(size_t)(ct * 16 + (lane >> 4) * 4 + j) * 128 + co * 16 + (lane & 15)];
    }
    wPack[gid] = f2b(v);
}

// =====================================================================
// K1: LN1 + roll + window-partition + QKV + attention + proj + residual
// (unchanged — measured at HBM roofline, ~46us)
// =====================================================================
__global__ __launch_bounds__(256, 3) void k_block1(
    const float* __restrict__ x,
    const float* __restrict__ ln1s, const float* __restrict__ ln1b,
    const unsigned short* __restrict__ qkvW, const float* __restrict__ qkvB,
    const float* __restrict__ relb,
    const unsigned short* __restrict__ projW, const float* __restrict__ projB,
    float* __restrict__ out)
{
    __shared__ unsigned short sm[4 * 6144];   // 48 KB
    __shared__ float sbias[196];
    const int tid = threadIdx.x;
    const int wave = tid >> 6, lane = tid & 63;
    const int g = lane >> 4, m16 = lane & 15;
    if (tid < 196) sbias[tid] = relb[tid];
    const int win0 = blockIdx.x * 4;
    const int winM = win0 + wave;
    const int bbM = winM >> 8, whM = (winM >> 4) & 15, wnM = winM & 15;

    // ---- phase A: LN1 + roll-gather -> A-tile [16][128] bf16, swizzled ----
    {
        float4 sc0 = *(const float4*)(ln1s + m16 * 8);
        float4 sc1 = *(const float4*)(ln1s + m16 * 8 + 4);
        float4 bi0 = *(const float4*)(ln1b + m16 * 8);
        float4 bi1 = *(const float4*)(ln1b + m16 * 8 + 4);
        #pragma unroll
        for (int it = 0; it < 4; ++it) {
            int tok = it * 4 + g;
            int ti = tok >> 2, tj = tok & 3;
            int hh = (whM * 4 + ti + 2) & 63, ww = (wnM * 4 + tj + 2) & 63;
            const float* xr = x + ((((size_t)bbM << 12) | (hh << 6) | ww) * 128) + m16 * 8;
            float4 v0 = *(const float4*)xr, v1 = *(const float4*)(xr + 4);
            float sum = v0.x + v0.y + v0.z + v0.w + v1.x + v1.y + v1.z + v1.w;
            float sq  = v0.x*v0.x + v0.y*v0.y + v0.z*v0.z + v0.w*v0.w
                      + v1.x*v1.x + v1.y*v1.y + v1.z*v1.z + v1.w*v1.w;
            #pragma unroll
            for (int m = 1; m < 16; m <<= 1) { sum += __shfl_xor(sum, m); sq += __shfl_xor(sq, m); }
            float mu = sum * 0.0078125f;
            float rstd = rsqrtf(sq * 0.0078125f - mu * mu + 1e-6f);
            us8 o;
            o[0] = f2b((v0.x - mu) * rstd * sc0.x + bi0.x);
            o[1] = f2b((v0.y - mu) * rstd * sc0.y + bi0.y);
            o[2] = f2b((v0.z - mu) * rstd * sc0.z + bi0.z);
            o[3] = f2b((v0.w - mu) * rstd * sc0.w + bi0.w);
            o[4] = f2b((v1.x - mu) * rstd * sc1.x + bi1.x);
            o[5] = f2b((v1.y - mu) * rstd * sc1.y + bi1.y);
            o[6] = f2b((v1.z - mu) * rstd * sc1.z + bi1.z);
            o[7] = f2b((v1.w - mu) * rstd * sc1.w + bi1.w);
            lds_st8(sm, wave * 12288 + tok * 256 + ((m16 * 16) ^ ((tok & 7) << 4)), o);
        }
    }
    __syncthreads();

    us8 afr[4][4];
    #pragma unroll
    for (int w = 0; w < 4; ++w)
        #pragma unroll
        for (int k = 0; k < 4; ++k)
            afr[w][k] = lds_ld8(sm, w * 12288 + m16 * 256 + ((k * 64 + g * 16) ^ ((m16 & 7) << 4)));
    __syncthreads();

    // ---- phase B: QKV GEMM, cols split by wave (96 each), 4-window B-reuse ----
    #pragma unroll
    for (int ct = 0; ct < 6; ++ct) {
        const int cb = wave * 96 + ct * 16;
        const unsigned short* bp = qkvW + (cb + m16) * 128 + g * 8;
        us8 b0 = *(const us8*)(bp);
        us8 b1 = *(const us8*)(bp + 32);
        us8 b2 = *(const us8*)(bp + 64);
        us8 b3 = *(const us8*)(bp + 96);
        f32x4 acc[4] = {{0.f,0.f,0.f,0.f},{0.f,0.f,0.f,0.f},{0.f,0.f,0.f,0.f},{0.f,0.f,0.f,0.f}};
        #pragma unroll
        for (int w = 0; w < 4; ++w) {
            acc[w] = mfma16(afr[w][0], b0, acc[w]);
            acc[w] = mfma16(afr[w][1], b1, acc[w]);
            acc[w] = mfma16(afr[w][2], b2, acc[w]);
            acc[w] = mfma16(afr[w][3], b3, acc[w]);
        }
        const int c = cb + m16;
        const float bias = qkvB[c];
        const int s = c >> 7;
        const int rem = c & 127, hq = rem >> 5, hd = rem & 31;
        #pragma unroll
        for (int w = 0; w < 4; ++w) {
            const int base = w * 12288;
            if (s == 2) {
                us4 pk;
                #pragma unroll
                for (int jj = 0; jj < 4; ++jj) pk[jj] = f2b(acc[w][jj] + bias);
                *(us4*)((char*)sm + base + 8192 + hq * 1024 + hd * 32 + g * 8) = pk;
            } else {
                #pragma unroll
                for (int jj = 0; jj < 4; ++jj) {
                    float v = acc[w][jj] + bias;
                    if (s == 0) v *= SCALE_Q;
                    int tok = g * 4 + jj;
                    *(unsigned short*)((char*)sm + base + s * 4096 + hq * 1024 + tok * 64 + hd * 2)
                        = f2b(v);
                }
            }
        }
    }
    __syncthreads();

    // ---- phase C: attention via MFMA (wave-local window) ----
    {
        const int base = wave * 12288;
        const int ti = m16 >> 2, tj = m16 & 3;
        const int hhq = whM * 4 + ti, wwq = wnM * 4 + tj;
        const int myid = (hhq < 60 ? 0 : (hhq < 62 ? 3 : 6)) + (wwq < 60 ? 0 : (wwq < 62 ? 1 : 2));
        f32x4 po[4][2];
        #pragma unroll
        for (int h = 0; h < 4; ++h) {
            us8 kf = lds_ld8(sm, base + 4096 + h * 1024 + m16 * 64 + g * 16);
            us8 qf = lds_ld8(sm, base +        h * 1024 + m16 * 64 + g * 16);
            f32x4 st = mfma16(kf, qf, (f32x4){0.f,0.f,0.f,0.f});
            float p[4];
            #pragma unroll
            for (int jj = 0; jj < 4; ++jj) {
                int kk = g * 4 + jj;
                int pi = kk >> 2, pj = kk & 3;
                int hhk = whM * 4 + pi, wwk = wnM * 4 + pj;
                int pid = (hhk < 60 ? 0 : (hhk < 62 ? 3 : 6)) + (wwk < 60 ? 0 : (wwk < 62 ? 1 : 2));
                float v = st[jj] + sbias[((ti - pi + 3) * 7 + (tj - pj + 3)) * 4 + h];
                p[jj] = (pid != myid) ? v - 100.f : v;
            }
            #pragma unroll
            for (int rep = 0; rep < 2; ++rep) {   // double softmax (faithful)
                float mx = fmaxf(fmaxf(p[0], p[1]), fmaxf(p[2], p[3]));
                mx = fmaxf(mx, __shfl_xor(mx, 16));
                mx = fmaxf(mx, __shfl_xor(mx, 32));
                float ssum = 0.f;
                #pragma unroll
                for (int jj = 0; jj < 4; ++jj) { p[jj] = __expf(p[jj] - mx); ssum += p[jj]; }
                ssum += __shfl_xor(ssum, 16);
                ssum += __shfl_xor(ssum, 32);
                float inv = 1.f / ssum;
                #pragma unroll
                for (int jj = 0; jj < 4; ++jj) p[jj] *= inv;
            }
            us4 pf;
            #pragma unroll
            for (int jj = 0; jj < 4; ++jj) pf[jj] = f2b(p[jj]);
            #pragma unroll
            for (int dh = 0; dh < 2; ++dh) {
                us4 vf = *(const us4*)((const char*)sm + base + 8192 + h * 1024
                                       + (dh * 16 + m16) * 32 + g * 8);
                po[h][dh] = mfma16k16(vf, pf, (f32x4){0.f,0.f,0.f,0.f});
            }
        }
        #pragma unroll
        for (int h = 0; h < 4; ++h)
            #pragma unroll
            for (int dh = 0; dh < 2; ++dh) {
                us4 pk;
                #pragma unroll
                for (int jj = 0; jj < 4; ++jj) pk[jj] = f2b(po[h][dh][jj]);
                *(us4*)((char*)sm + base + m16 * 256
                        + ((h * 64 + dh * 32 + g * 8) ^ ((m16 & 7) << 4))) = pk;
            }
    }
    __syncthreads();

    // ---- phase D: proj (cols split by wave: 32 each) + unroll-scatter + residual ----
    {
        us8 cfr[4][4];
        #pragma unroll
        for (int w = 0; w < 4; ++w)
            #pragma unroll
            for (int k = 0; k < 4; ++k)
                cfr[w][k] = lds_ld8(sm, w * 12288 + m16 * 256 + ((k * 64 + g * 16) ^ ((m16 & 7) << 4)));
        #pragma unroll
        for (int ct = 0; ct < 2; ++ct) {
            const int c = wave * 32 + ct * 16 + m16;
            const unsigned short* bp = projW + c * 128 + g * 8;
            us8 b0 = *(const us8*)(bp);
            us8 b1 = *(const us8*)(bp + 32);
            us8 b2 = *(const us8*)(bp + 64);
            us8 b3 = *(const us8*)(bp + 96);
            const float pb = projB[c];
            #pragma unroll
            for (int w = 0; w < 4; ++w) {
                f32x4 acc = {0.f, 0.f, 0.f, 0.f};
                acc = mfma16(cfr[w][0], b0, acc);
                acc = mfma16(cfr[w][1], b1, acc);
                acc = mfma16(cfr[w][2], b2, acc);
                acc = mfma16(cfr[w][3], b3, acc);
                const int winw = win0 + w;
                const int bb = winw >> 8, wh = (winw >> 4) & 15, wn = winw & 15;
                #pragma unroll
                for (int jj = 0; jj < 4; ++jj) {
                    int tok = g * 4 + jj;
                    int hh3 = (wh * 4 + (tok >> 2) + 2) & 63;
                    int ww3 = (wn * 4 + (tok & 3) + 2) & 63;
                    size_t t = (((size_t)bb << 12) | (hh3 << 6) | ww3);
                    out[t * 128 + c] = acc[jj] + pb + x[t * 128 + c];
                }
            }
        }
    }
}

// =====================================================================
// K2 v4: LN2 + FC1 + GELU + FC2 + residual. Hidden in registers.
// 8 waves x 32 rows = 256 rows/block. LDS: 8 x 4KB wave-private LN
// scratch (transient, no barriers) + 2 x 8KB weight staging = 48KB
// -> 3 blocks/CU = 24 waves/CU.
// =====================================================================
__global__ __launch_bounds__(512, 6) void k_block2(
    float* __restrict__ out,
    const float* __restrict__ ln2s, const float* __restrict__ ln2b,
    const unsigned short* __restrict__ wPack,
    const float* __restrict__ fc1B, const float* __restrict__ fc2B)
{
    __shared__ unsigned short scratch[8][2048];   // 4KB per wave (16 rows x 256B)
    __shared__ unsigned short wbuf[2][4096];      // 2 x 8KB weight staging
    const int tid = threadIdx.x;
    const int wave = tid >> 6, lane = tid & 63;
    const int g = lane >> 4, m16 = lane & 15;
    const size_t r0 = (size_t)blockIdx.x * 256;

    // ---- stage slice 0 (all 512 threads, one 16B gload_lds each) ----
    {
        const unsigned short* src = wPack + tid * 8;
        unsigned short* dst = &wbuf[0][wave * 512];
#if __has_builtin(__builtin_amdgcn_global_load_lds)
        __builtin_amdgcn_global_load_lds(
            (const __attribute__((address_space(1))) void*)src,
            (__attribute__((address_space(3))) void*)dst, 16, 0, 0);
#else
        *(us8*)(dst + lane * 8) = *(const us8*)src;
#endif
    }

    // ---- LN2: 16 rows at a time through wave-private scratch, no barriers ----
    float4 sc0 = *(const float4*)(ln2s + m16 * 8);
    float4 sc1 = *(const float4*)(ln2s + m16 * 8 + 4);
    float4 bi0 = *(const float4*)(ln2b + m16 * 8);
    float4 bi1 = *(const float4*)(ln2b + m16 * 8 + 4);
    us8 bx[2][4];
    #pragma unroll
    for (int rt = 0; rt < 2; ++rt) {
        #pragma unroll
        for (int it = 0; it < 4; ++it) {
            int lr = it * 4 + g;                             // 0..15 local
            const float* xr = out + (r0 + wave * 32 + rt * 16 + lr) * 128 + m16 * 8;
            float4 v0 = *(const float4*)xr, v1 = *(const float4*)(xr + 4);
            float sum = v0.x + v0.y + v0.z + v0.w + v1.x + v1.y + v1.z + v1.w;
            float sq  = v0.x*v0.x + v0.y*v0.y + v0.z*v0.z + v0.w*v0.w
                      + v1.x*v1.x + v1.y*v1.y + v1.z*v1.z + v1.w*v1.w;
            #pragma unroll
            for (int m = 1; m < 16; m <<= 1) { sum += __shfl_xor(sum, m); sq += __shfl_xor(sq, m); }
            float mu = sum * 0.0078125f;
            float rstd = rsqrtf(sq * 0.0078125f - mu * mu + 1e-6f);
            us8 o;
            o[0] = f2b((v0.x - mu) * rstd * sc0.x + bi0.x);
            o[1] = f2b((v0.y - mu) * rstd * sc0.y + bi0.y);
            o[2] = f2b((v0.z - mu) * rstd * sc0.z + bi0.z);
            o[3] = f2b((v0.w - mu) * rstd * sc0.w + bi0.w);
            o[4] = f2b((v1.x - mu) * rstd * sc1.x + bi1.x);
            o[5] = f2b((v1.y - mu) * rstd * sc1.y + bi1.y);
            o[6] = f2b((v1.z - mu) * rstd * sc1.z + bi1.z);
            o[7] = f2b((v1.w - mu) * rstd * sc1.w + bi1.w);
            lds_st8(&scratch[wave][0], lr * 256 + ((m16 * 16) ^ ((lr & 7) << 4)), o);
        }
        // read this 16-row tile's B-frags (wave-local, lgkm-ordered)
        #pragma unroll
        for (int kk = 0; kk < 4; ++kk)
            bx[rt][kk] = lds_ld8(&scratch[wave][0],
                                 m16 * 256 + ((kk * 64 + g * 16) ^ ((m16 & 7) << 4)));
    }
    __syncthreads();   // slice-0 staging + all waves ready

    f32x4 accO[2][8];
    #pragma unroll
    for (int rt = 0; rt < 2; ++rt)
        #pragma unroll
        for (int co = 0; co < 8; ++co) accO[rt][co] = (f32x4){0.f, 0.f, 0.f, 0.f};

    #pragma unroll 2
    for (int ct = 0; ct < 32; ++ct) {
        // stage next slice (issue-early; end-of-iter barrier covers visibility)
        if (ct < 31) {
            const unsigned short* src = wPack + (ct + 1) * 4096 + tid * 8;
            unsigned short* dst = &wbuf[(ct + 1) & 1][wave * 512];
#if __has_builtin(__builtin_amdgcn_global_load_lds)
            __builtin_amdgcn_global_load_lds(
                (const __attribute__((address_space(1))) void*)src,
                (__attribute__((address_space(3))) void*)dst, 16, 0, 0);
#else
            *(us8*)(dst + lane * 8) = *(const us8*)src;
#endif
        }
        const char* wb = (const char*)&wbuf[ct & 1][0];
        // FC1^T: h{rt}[jj] = hid[row = wave*32+rt*16+m16][col = ct*16 + g*4 + jj]
        us8 aw0 = *(const us8*)(wb + 0 * 1024 + lane * 16);
        us8 aw1 = *(const us8*)(wb + 1 * 1024 + lane * 16);
        us8 aw2 = *(const us8*)(wb + 2 * 1024 + lane * 16);
        us8 aw3 = *(const us8*)(wb + 3 * 1024 + lane * 16);
        f32x4 h0 = {0.f, 0.f, 0.f, 0.f}, h1 = {0.f, 0.f, 0.f, 0.f};
        h0 = mfma16(aw0, bx[0][0], h0);
        h0 = mfma16(aw1, bx[0][1], h0);
        h0 = mfma16(aw2, bx[0][2], h0);
        h0 = mfma16(aw3, bx[0][3], h0);
        h1 = mfma16(aw0, bx[1][0], h1);
        h1 = mfma16(aw1, bx[1][1], h1);
        h1 = mfma16(aw2, bx[1][2], h1);
        h1 = mfma16(aw3, bx[1][3], h1);
        float4 b1v = *(const float4*)(fc1B + ct * 16 + g * 4);
        us4 pa0, pa1;
        #pragma unroll
        for (int jj = 0; jj < 4; ++jj) {
            float v = h0[jj] + ((const float*)&b1v)[jj];
            float z = v + 0.044715f * v * v * v;
            float e = __expf(-1.5957691216057308f * z);
            pa0[jj] = f2b(v * __builtin_amdgcn_rcpf(1.f + e));
            float w = h1[jj] + ((const float*)&b1v)[jj];
            float z2 = w + 0.044715f * w * w * w;
            float e2 = __expf(-1.5957691216057308f * z2);
            pa1[jj] = f2b(w * __builtin_amdgcn_rcpf(1.f + e2));
        }
        // FC2 partial-K accumulate (K=16 MFMA), B-frags from LDS
        #pragma unroll
        for (int co = 0; co < 8; ++co) {
            us4 bw = *(const us4*)(wb + 4096 + co * 512 + lane * 8);
            accO[0][co] = mfma16k16(pa0, bw, accO[0][co]);
            accO[1][co] = mfma16k16(pa1, bw, accO[1][co]);
        }
        __syncthreads();
    }

    // ---- epilogue: bias + residual, in-place fp32 ----
    #pragma unroll
    for (int rt = 0; rt < 2; ++rt)
        #pragma unroll
        for (int co = 0; co < 8; ++co) {
            int col = co * 16 + m16;
            float b2v = fc2B[col];
            #pragma unroll
            for (int jj = 0; jj < 4; ++jj) {
                size_t row = r0 + wave * 32 + rt * 16 + g * 4 + jj;
                float* op = out + row * 128 + col;
                *op = accO[rt][co][jj] + b2v + *op;
            }
        }
}

// ---------- launch ----------
extern "C" void kernel_launch(void* const* d_in, const int* in_sizes, int n_in,
                              void* d_out, int out_size, void* d_ws, size_t ws_size,
                              hipStream_t stream) {
    const float* x        = (const float*)d_in[0];
    const float* ln1_s    = (const float*)d_in[1];
    const float* ln1_b    = (const float*)d_in[2];
    const float* qkv_w    = (const float*)d_in[3];
    const float* qkv_b    = (const float*)d_in[4];
    const float* rel_bias = (const float*)d_in[5];
    const float* proj_w   = (const float*)d_in[6];
    const float* proj_b   = (const float*)d_in[7];
    const float* ln2_s    = (const float*)d_in[8];
    const float* ln2_b    = (const float*)d_in[9];
    const float* fc1_w    = (const float*)d_in[10];
    const float* fc1_b    = (const float*)d_in[11];
    const float* fc2_w    = (const float*)d_in[12];
    const float* fc2_b    = (const float*)d_in[13];
    float* out = (float*)d_out;
    char* ws = (char*)d_ws;

    unsigned short* qkv_wt  = (unsigned short*)(ws);             // 384x128 bf16 (96KB)
    unsigned short* proj_wt = (unsigned short*)(ws + 98304);     // 128x128 (32KB)
    unsigned short* wpack   = (unsigned short*)(ws + 131072);    // 32x8KB = 256KB

    k_transpose<<<192, 256, 0, stream>>>(qkv_w, qkv_wt, 128, 384);
    k_transpose<<<64,  256, 0, stream>>>(proj_w, proj_wt, 128, 128);
    k_pack_mlp<<<512, 256, 0, stream>>>(fc1_w, fc2_w, wpack);

    k_block1<<<4096, 256, 0, stream>>>(x, ln1_s, ln1_b, qkv_wt, qkv_b, rel_bias,
                                       proj_wt, proj_b, out);
    k_block2<<<1024, 512, 0, stream>>>(out, ln2_s, ln2_b, wpack, fc1_b, fc2_b);
}

// Round 7
// 285.148 us; speedup vs baseline: 2.5217x; 2.5217x over previous
//
#include <hip/hip_runtime.h>

typedef __bf16 bf16x8 __attribute__((ext_vector_type(8)));
typedef __bf16 bf16x4 __attribute__((ext_vector_type(4)));
typedef float f32x4 __attribute__((ext_vector_type(4)));
typedef unsigned short us8 __attribute__((ext_vector_type(8)));
typedef unsigned short us4 __attribute__((ext_vector_type(4)));
typedef short sh4 __attribute__((ext_vector_type(4)));

#define SCALE_Q 0.17677669529663687f  // 32^-0.5

__device__ __forceinline__ unsigned short f2b(float f) {
    __bf16 h = (__bf16)f;                       // RNE, packs to v_cvt_pk_bf16_f32
    return __builtin_bit_cast(unsigned short, h);
}
__device__ __forceinline__ float b2f(unsigned short h) {
    union { unsigned u; float f; } v; v.u = ((unsigned)h) << 16;
    return v.f;
}
__device__ __forceinline__ f32x4 mfma16(us8 a, us8 b, f32x4 c) {
    return __builtin_amdgcn_mfma_f32_16x16x32_bf16(
        __builtin_bit_cast(bf16x8, a), __builtin_bit_cast(bf16x8, b), c, 0, 0, 0);
}

// K=16 bf16 MFMA. A/B frag: 4 bf16, elem k=(lane>>4)*4+j. C/D standard.
#if __has_builtin(__builtin_amdgcn_mfma_f32_16x16x16bf16_1k)
__device__ __forceinline__ f32x4 mfma16k16(us4 a, us4 b, f32x4 c) {
    return __builtin_amdgcn_mfma_f32_16x16x16bf16_1k(
        __builtin_bit_cast(sh4, a), __builtin_bit_cast(sh4, b), c, 0, 0, 0);
}
#elif __has_builtin(__builtin_amdgcn_mfma_f32_16x16x16_bf16)
__device__ __forceinline__ f32x4 mfma16k16(us4 a, us4 b, f32x4 c) {
    return __builtin_amdgcn_mfma_f32_16x16x16_bf16(
        __builtin_bit_cast(bf16x4, a), __builtin_bit_cast(bf16x4, b), c, 0, 0, 0);
}
#else
__device__ __forceinline__ f32x4 mfma16k16(us4 a, us4 b, f32x4 c) {
    asm volatile("v_mfma_f32_16x16x16_bf16 %0, %1, %2, %0"
                 : "+v"(c) : "v"(a), "v"(b));
    return c;
}
#endif

__device__ __forceinline__ us8 lds_ld8(const unsigned short* base, int byteoff) {
    return *(const us8*)((const char*)base + byteoff);
}
__device__ __forceinline__ void lds_st8(unsigned short* base, int byteoff, us8 v) {
    *(us8*)((char*)base + byteoff) = v;
}

// ---------- weight transpose + bf16 convert:  dst[c][r] = src[r][c] ----------
__global__ void k_transpose(const float* __restrict__ src, unsigned short* __restrict__ dst,
                            int R, int C) {
    int idx = blockIdx.x * 256 + threadIdx.x;
    if (idx >= R * C) return;
    int r = idx / C, c = idx - r * C;
    dst[c * R + r] = f2b(src[idx]);
}

// ---------- pack MLP weights into per-ct 8KB fragment slices ----------
__global__ void k_pack_mlp(const float* __restrict__ fc1_w, const float* __restrict__ fc2_w,
                           unsigned short* __restrict__ wPack) {
    int gid = blockIdx.x * 256 + threadIdx.x;          // 131072 shorts total
    int ct = gid >> 12;                                 // 4096 shorts / slice
    int byte = (gid & 4095) * 2;
    float v;
    if (byte < 4096) {
        int kk = byte >> 10, rem = byte & 1023;
        int lane = rem >> 4, j = (rem & 15) >> 1;
        v = fc1_w[(size_t)(kk * 32 + (lane >> 4) * 8 + j) * 512 + ct * 16 + (lane & 15)];
    } else {
        int b2 = byte - 4096;
        int co = b2 >> 9, rem = b2 & 511;
        int lane = rem >> 3, j = (rem & 7) >> 1;
        v = fc2_w[(size_t)(ct * 16 + (lane >> 4) * 4 + j) * 128 + co * 16 + (lane & 15)];
    }
    wPack[gid] = f2b(v);
}

// =====================================================================
// K1: LN1 + roll + window-partition + QKV + attention + proj + residual
// (unchanged — measured at HBM roofline, ~46us)
// =====================================================================
__global__ __launch_bounds__(256, 3) void k_block1(
    const float* __restrict__ x,
    const float* __restrict__ ln1s, const float* __restrict__ ln1b,
    const unsigned short* __restrict__ qkvW, const float* __restrict__ qkvB,
    const float* __restrict__ relb,
    const unsigned short* __restrict__ projW, const float* __restrict__ projB,
    float* __restrict__ out)
{
    __shared__ unsigned short sm[4 * 6144];   // 48 KB
    __shared__ float sbias[196];
    const int tid = threadIdx.x;
    const int wave = tid >> 6, lane = tid & 63;
    const int g = lane >> 4, m16 = lane & 15;
    if (tid < 196) sbias[tid] = relb[tid];
    const int win0 = blockIdx.x * 4;
    const int winM = win0 + wave;
    const int bbM = winM >> 8, whM = (winM >> 4) & 15, wnM = winM & 15;

    // ---- phase A: LN1 + roll-gather -> A-tile [16][128] bf16, swizzled ----
    {
        float4 sc0 = *(const float4*)(ln1s + m16 * 8);
        float4 sc1 = *(const float4*)(ln1s + m16 * 8 + 4);
        float4 bi0 = *(const float4*)(ln1b + m16 * 8);
        float4 bi1 = *(const float4*)(ln1b + m16 * 8 + 4);
        #pragma unroll
        for (int it = 0; it < 4; ++it) {
            int tok = it * 4 + g;
            int ti = tok >> 2, tj = tok & 3;
            int hh = (whM * 4 + ti + 2) & 63, ww = (wnM * 4 + tj + 2) & 63;
            const float* xr = x + ((((size_t)bbM << 12) | (hh << 6) | ww) * 128) + m16 * 8;
            float4 v0 = *(const float4*)xr, v1 = *(const float4*)(xr + 4);
            float sum = v0.x + v0.y + v0.z + v0.w + v1.x + v1.y + v1.z + v1.w;
            float sq  = v0.x*v0.x + v0.y*v0.y + v0.z*v0.z + v0.w*v0.w
                      + v1.x*v1.x + v1.y*v1.y + v1.z*v1.z + v1.w*v1.w;
            #pragma unroll
            for (int m = 1; m < 16; m <<= 1) { sum += __shfl_xor(sum, m); sq += __shfl_xor(sq, m); }
            float mu = sum * 0.0078125f;
            float rstd = rsqrtf(sq * 0.0078125f - mu * mu + 1e-6f);
            us8 o;
            o[0] = f2b((v0.x - mu) * rstd * sc0.x + bi0.x);
            o[1] = f2b((v0.y - mu) * rstd * sc0.y + bi0.y);
            o[2] = f2b((v0.z - mu) * rstd * sc0.z + bi0.z);
            o[3] = f2b((v0.w - mu) * rstd * sc0.w + bi0.w);
            o[4] = f2b((v1.x - mu) * rstd * sc1.x + bi1.x);
            o[5] = f2b((v1.y - mu) * rstd * sc1.y + bi1.y);
            o[6] = f2b((v1.z - mu) * rstd * sc1.z + bi1.z);
            o[7] = f2b((v1.w - mu) * rstd * sc1.w + bi1.w);
            lds_st8(sm, wave * 12288 + tok * 256 + ((m16 * 16) ^ ((tok & 7) << 4)), o);
        }
    }
    __syncthreads();

    us8 afr[4][4];
    #pragma unroll
    for (int w = 0; w < 4; ++w)
        #pragma unroll
        for (int k = 0; k < 4; ++k)
            afr[w][k] = lds_ld8(sm, w * 12288 + m16 * 256 + ((k * 64 + g * 16) ^ ((m16 & 7) << 4)));
    __syncthreads();

    // ---- phase B: QKV GEMM, cols split by wave (96 each), 4-window B-reuse ----
    #pragma unroll
    for (int ct = 0; ct < 6; ++ct) {
        const int cb = wave * 96 + ct * 16;
        const unsigned short* bp = qkvW + (cb + m16) * 128 + g * 8;
        us8 b0 = *(const us8*)(bp);
        us8 b1 = *(const us8*)(bp + 32);
        us8 b2 = *(const us8*)(bp + 64);
        us8 b3 = *(const us8*)(bp + 96);
        f32x4 acc[4] = {{0.f,0.f,0.f,0.f},{0.f,0.f,0.f,0.f},{0.f,0.f,0.f,0.f},{0.f,0.f,0.f,0.f}};
        #pragma unroll
        for (int w = 0; w < 4; ++w) {
            acc[w] = mfma16(afr[w][0], b0, acc[w]);
            acc[w] = mfma16(afr[w][1], b1, acc[w]);
            acc[w] = mfma16(afr[w][2], b2, acc[w]);
            acc[w] = mfma16(afr[w][3], b3, acc[w]);
        }
        const int c = cb + m16;
        const float bias = qkvB[c];
        const int s = c >> 7;
        const int rem = c & 127, hq = rem >> 5, hd = rem & 31;
        #pragma unroll
        for (int w = 0; w < 4; ++w) {
            const int base = w * 12288;
            if (s == 2) {
                us4 pk;
                #pragma unroll
                for (int jj = 0; jj < 4; ++jj) pk[jj] = f2b(acc[w][jj] + bias);
                *(us4*)((char*)sm + base + 8192 + hq * 1024 + hd * 32 + g * 8) = pk;
            } else {
                #pragma unroll
                for (int jj = 0; jj < 4; ++jj) {
                    float v = acc[w][jj] + bias;
                    if (s == 0) v *= SCALE_Q;
                    int tok = g * 4 + jj;
                    *(unsigned short*)((char*)sm + base + s * 4096 + hq * 1024 + tok * 64 + hd * 2)
                        = f2b(v);
                }
            }
        }
    }
    __syncthreads();

    // ---- phase C: attention via MFMA (wave-local window) ----
    {
        const int base = wave * 12288;
        const int ti = m16 >> 2, tj = m16 & 3;
        const int hhq = whM * 4 + ti, wwq = wnM * 4 + tj;
        const int myid = (hhq < 60 ? 0 : (hhq < 62 ? 3 : 6)) + (wwq < 60 ? 0 : (wwq < 62 ? 1 : 2));
        f32x4 po[4][2];
        #pragma unroll
        for (int h = 0; h < 4; ++h) {
            us8 kf = lds_ld8(sm, base + 4096 + h * 1024 + m16 * 64 + g * 16);
            us8 qf = lds_ld8(sm, base +        h * 1024 + m16 * 64 + g * 16);
            f32x4 st = mfma16(kf, qf, (f32x4){0.f,0.f,0.f,0.f});
            float p[4];
            #pragma unroll
            for (int jj = 0; jj < 4; ++jj) {
                int kk = g * 4 + jj;
                int pi = kk >> 2, pj = kk & 3;
                int hhk = whM * 4 + pi, wwk = wnM * 4 + pj;
                int pid = (hhk < 60 ? 0 : (hhk < 62 ? 3 : 6)) + (wwk < 60 ? 0 : (wwk < 62 ? 1 : 2));
                float v = st[jj] + sbias[((ti - pi + 3) * 7 + (tj - pj + 3)) * 4 + h];
                p[jj] = (pid != myid) ? v - 100.f : v;
            }
            #pragma unroll
            for (int rep = 0; rep < 2; ++rep) {   // double softmax (faithful)
                float mx = fmaxf(fmaxf(p[0], p[1]), fmaxf(p[2], p[3]));
                mx = fmaxf(mx, __shfl_xor(mx, 16));
                mx = fmaxf(mx, __shfl_xor(mx, 32));
                float ssum = 0.f;
                #pragma unroll
                for (int jj = 0; jj < 4; ++jj) { p[jj] = __expf(p[jj] - mx); ssum += p[jj]; }
                ssum += __shfl_xor(ssum, 16);
                ssum += __shfl_xor(ssum, 32);
                float inv = 1.f / ssum;
                #pragma unroll
                for (int jj = 0; jj < 4; ++jj) p[jj] *= inv;
            }
            us4 pf;
            #pragma unroll
            for (int jj = 0; jj < 4; ++jj) pf[jj] = f2b(p[jj]);
            #pragma unroll
            for (int dh = 0; dh < 2; ++dh) {
                us4 vf = *(const us4*)((const char*)sm + base + 8192 + h * 1024
                                       + (dh * 16 + m16) * 32 + g * 8);
                po[h][dh] = mfma16k16(vf, pf, (f32x4){0.f,0.f,0.f,0.f});
            }
        }
        #pragma unroll
        for (int h = 0; h < 4; ++h)
            #pragma unroll
            for (int dh = 0; dh < 2; ++dh) {
                us4 pk;
                #pragma unroll
                for (int jj = 0; jj < 4; ++jj) pk[jj] = f2b(po[h][dh][jj]);
                *(us4*)((char*)sm + base + m16 * 256
                        + ((h * 64 + dh * 32 + g * 8) ^ ((m16 & 7) << 4))) = pk;
            }
    }
    __syncthreads();

    // ---- phase D: proj (cols split by wave: 32 each) + unroll-scatter + residual ----
    {
        us8 cfr[4][4];
        #pragma unroll
        for (int w = 0; w < 4; ++w)
            #pragma unroll
            for (int k = 0; k < 4; ++k)
                cfr[w][k] = lds_ld8(sm, w * 12288 + m16 * 256 + ((k * 64 + g * 16) ^ ((m16 & 7) << 4)));
        #pragma unroll
        for (int ct = 0; ct < 2; ++ct) {
            const int c = wave * 32 + ct * 16 + m16;
            const unsigned short* bp = projW + c * 128 + g * 8;
            us8 b0 = *(const us8*)(bp);
            us8 b1 = *(const us8*)(bp + 32);
            us8 b2 = *(const us8*)(bp + 64);
            us8 b3 = *(const us8*)(bp + 96);
            const float pb = projB[c];
            #pragma unroll
            for (int w = 0; w < 4; ++w) {
                f32x4 acc = {0.f, 0.f, 0.f, 0.f};
                acc = mfma16(cfr[w][0], b0, acc);
                acc = mfma16(cfr[w][1], b1, acc);
                acc = mfma16(cfr[w][2], b2, acc);
                acc = mfma16(cfr[w][3], b3, acc);
                const int winw = win0 + w;
                const int bb = winw >> 8, wh = (winw >> 4) & 15, wn = winw & 15;
                #pragma unroll
                for (int jj = 0; jj < 4; ++jj) {
                    int tok = g * 4 + jj;
                    int hh3 = (wh * 4 + (tok >> 2) + 2) & 63;
                    int ww3 = (wn * 4 + (tok & 3) + 2) & 63;
                    size_t t = (((size_t)bb << 12) | (hh3 << 6) | ww3);
                    out[t * 128 + c] = acc[jj] + pb + x[t * 128 + c];
                }
            }
        }
    }
}

// =====================================================================
// K2 v5: LN2 + FC1 + GELU + FC2 + residual. Hidden in registers.
// NO barriers, NO cross-wave sharing: each wave streams packed weight
// fragments with coalesced global loads (L1/L2-hot), 1-deep rotation.
// 4 waves x 32 rows = 128 rows/block. LDS = 16KB wave-private scratch.
// =====================================================================
__global__ __launch_bounds__(256, 3) void k_block2(
    float* __restrict__ out,
    const float* __restrict__ ln2s, const float* __restrict__ ln2b,
    const unsigned short* __restrict__ wPack,
    const float* __restrict__ fc1B, const float* __restrict__ fc2B)
{
    __shared__ unsigned short scratch[4][2048];   // 4KB per wave (16 rows x 256B)
    const int tid = threadIdx.x;
    const int wave = tid >> 6, lane = tid & 63;
    const int g = lane >> 4, m16 = lane & 15;
    const size_t r0 = (size_t)blockIdx.x * 128;

    // ---- LN2: 16 rows at a time through wave-private scratch, no barriers ----
    float4 sc0 = *(const float4*)(ln2s + m16 * 8);
    float4 sc1 = *(const float4*)(ln2s + m16 * 8 + 4);
    float4 bi0 = *(const float4*)(ln2b + m16 * 8);
    float4 bi1 = *(const float4*)(ln2b + m16 * 8 + 4);
    us8 bx[2][4];
    #pragma unroll
    for (int rt = 0; rt < 2; ++rt) {
        #pragma unroll
        for (int it = 0; it < 4; ++it) {
            int lr = it * 4 + g;                             // 0..15 local
            const float* xr = out + (r0 + wave * 32 + rt * 16 + lr) * 128 + m16 * 8;
            float4 v0 = *(const float4*)xr, v1 = *(const float4*)(xr + 4);
            float sum = v0.x + v0.y + v0.z + v0.w + v1.x + v1.y + v1.z + v1.w;
            float sq  = v0.x*v0.x + v0.y*v0.y + v0.z*v0.z + v0.w*v0.w
                      + v1.x*v1.x + v1.y*v1.y + v1.z*v1.z + v1.w*v1.w;
            #pragma unroll
            for (int m = 1; m < 16; m <<= 1) { sum += __shfl_xor(sum, m); sq += __shfl_xor(sq, m); }
            float mu = sum * 0.0078125f;
            float rstd = rsqrtf(sq * 0.0078125f - mu * mu + 1e-6f);
            us8 o;
            o[0] = f2b((v0.x - mu) * rstd * sc0.x + bi0.x);
            o[1] = f2b((v0.y - mu) * rstd * sc0.y + bi0.y);
            o[2] = f2b((v0.z - mu) * rstd * sc0.z + bi0.z);
            o[3] = f2b((v0.w - mu) * rstd * sc0.w + bi0.w);
            o[4] = f2b((v1.x - mu) * rstd * sc1.x + bi1.x);
            o[5] = f2b((v1.y - mu) * rstd * sc1.y + bi1.y);
            o[6] = f2b((v1.z - mu) * rstd * sc1.z + bi1.z);
            o[7] = f2b((v1.w - mu) * rstd * sc1.w + bi1.w);
            lds_st8(&scratch[wave][0], lr * 256 + ((m16 * 16) ^ ((lr & 7) << 4)), o);
        }
        // read this 16-row tile's B-frags (wave-local, lgkm-ordered)
        #pragma unroll
        for (int kk = 0; kk < 4; ++kk)
            bx[rt][kk] = lds_ld8(&scratch[wave][0],
                                 m16 * 256 + ((kk * 64 + g * 16) ^ ((m16 & 7) << 4)));
    }

    f32x4 accO[2][8];
    #pragma unroll
    for (int rt = 0; rt < 2; ++rt)
        #pragma unroll
        for (int co = 0; co < 8; ++co) accO[rt][co] = (f32x4){0.f, 0.f, 0.f, 0.f};

    // ---- prologue: load aw for ct=0 (coalesced 1KB dwordx4 loads) ----
    us8 aw0 = *(const us8*)(wPack + 0 * 512 + lane * 8);
    us8 aw1 = *(const us8*)(wPack + 1 * 512 + lane * 8);
    us8 aw2 = *(const us8*)(wPack + 2 * 512 + lane * 8);
    us8 aw3 = *(const us8*)(wPack + 3 * 512 + lane * 8);

    for (int ct = 0; ct < 32; ++ct) {
        const unsigned short* ws_ = wPack + ct * 4096;
        // bw loads for this iter (issued early; used after FC1+GELU)
        us4 bw[8];
        #pragma unroll
        for (int co = 0; co < 8; ++co)
            bw[co] = *(const us4*)(ws_ + 2048 + co * 256 + lane * 4);
        // prefetch next iter's aw
        const unsigned short* wn = wPack + (ct < 31 ? (ct + 1) * 4096 : ct * 4096);
        us8 na0 = *(const us8*)(wn + 0 * 512 + lane * 8);
        us8 na1 = *(const us8*)(wn + 1 * 512 + lane * 8);
        us8 na2 = *(const us8*)(wn + 2 * 512 + lane * 8);
        us8 na3 = *(const us8*)(wn + 3 * 512 + lane * 8);
        // FC1^T: h{rt}[jj] = hid[row = wave*32+rt*16+m16][col = ct*16 + g*4 + jj]
        f32x4 h0 = {0.f, 0.f, 0.f, 0.f}, h1 = {0.f, 0.f, 0.f, 0.f};
        h0 = mfma16(aw0, bx[0][0], h0);
        h0 = mfma16(aw1, bx[0][1], h0);
        h0 = mfma16(aw2, bx[0][2], h0);
        h0 = mfma16(aw3, bx[0][3], h0);
        h1 = mfma16(aw0, bx[1][0], h1);
        h1 = mfma16(aw1, bx[1][1], h1);
        h1 = mfma16(aw2, bx[1][2], h1);
        h1 = mfma16(aw3, bx[1][3], h1);
        float4 b1v = *(const float4*)(fc1B + ct * 16 + g * 4);
        us4 pa0, pa1;
        #pragma unroll
        for (int jj = 0; jj < 4; ++jj) {
            float v = h0[jj] + ((const float*)&b1v)[jj];
            float z = v + 0.044715f * v * v * v;
            float e = __builtin_amdgcn_exp2f(-2.3022082f * z);   // exp(-1.59577 z)
            pa0[jj] = f2b(v * __builtin_amdgcn_rcpf(1.f + e));
            float w = h1[jj] + ((const float*)&b1v)[jj];
            float z2 = w + 0.044715f * w * w * w;
            float e2 = __builtin_amdgcn_exp2f(-2.3022082f * z2);
            pa1[jj] = f2b(w * __builtin_amdgcn_rcpf(1.f + e2));
        }
        // FC2 partial-K accumulate (K=16 MFMA)
        #pragma unroll
        for (int co = 0; co < 8; ++co) {
            accO[0][co] = mfma16k16(pa0, bw[co], accO[0][co]);
            accO[1][co] = mfma16k16(pa1, bw[co], accO[1][co]);
        }
        aw0 = na0; aw1 = na1; aw2 = na2; aw3 = na3;
    }

    // ---- epilogue: bias + residual, in-place fp32 ----
    #pragma unroll
    for (int rt = 0; rt < 2; ++rt)
        #pragma unroll
        for (int co = 0; co < 8; ++co) {
            int col = co * 16 + m16;
            float b2v = fc2B[col];
            #pragma unroll
            for (int jj = 0; jj < 4; ++jj) {
                size_t row = r0 + wave * 32 + rt * 16 + g * 4 + jj;
                float* op = out + row * 128 + col;
                *op = accO[rt][co][jj] + b2v + *op;
            }
        }
}

// ---------- launch ----------
extern "C" void kernel_launch(void* const* d_in, const int* in_sizes, int n_in,
                              void* d_out, int out_size, void* d_ws, size_t ws_size,
                              hipStream_t stream) {
    const float* x        = (const float*)d_in[0];
    const float* ln1_s    = (const float*)d_in[1];
    const float* ln1_b    = (const float*)d_in[2];
    const float* qkv_w    = (const float*)d_in[3];
    const float* qkv_b    = (const float*)d_in[4];
    const float* rel_bias = (const float*)d_in[5];
    const float* proj_w   = (const float*)d_in[6];
    const float* proj_b   = (const float*)d_in[7];
    const float* ln2_s    = (const float*)d_in[8];
    const float* ln2_b    = (const float*)d_in[9];
    const float* fc1_w    = (const float*)d_in[10];
    const float* fc1_b    = (const float*)d_in[11];
    const float* fc2_w    = (const float*)d_in[12];
    const float* fc2_b    = (const float*)d_in[13];
    float* out = (float*)d_out;
    char* ws = (char*)d_ws;

    unsigned short* qkv_wt  = (unsigned short*)(ws);             // 384x128 bf16 (96KB)
    unsigned short* proj_wt = (unsigned short*)(ws + 98304);     // 128x128 (32KB)
    unsigned short* wpack   = (unsigned short*)(ws + 131072);    // 32x8KB = 256KB

    k_transpose<<<192, 256, 0, stream>>>(qkv_w, qkv_wt, 128, 384);
    k_transpose<<<64,  256, 0, stream>>>(proj_w, proj_wt, 128, 128);
    k_pack_mlp<<<512, 256, 0, stream>>>(fc1_w, fc2_w, wpack);

    k_block1<<<4096, 256, 0, stream>>>(x, ln1_s, ln1_b, qkv_wt, qkv_b, rel_bias,
                                       proj_wt, proj_b, out);
    k_block2<<<2048, 256, 0, stream>>>(out, ln2_s, ln2_b, wpack, fc1_b, fc2_b);
}

// Round 8
// 253.323 us; speedup vs baseline: 2.8385x; 1.1256x over previous
//
#include <hip/hip_runtime.h>

typedef __bf16 bf16x8 __attribute__((ext_vector_type(8)));
typedef __bf16 bf16x4 __attribute__((ext_vector_type(4)));
typedef float f32x4 __attribute__((ext_vector_type(4)));
typedef unsigned short us8 __attribute__((ext_vector_type(8)));
typedef unsigned short us4 __attribute__((ext_vector_type(4)));
typedef short sh4 __attribute__((ext_vector_type(4)));

#define SCALE_Q 0.17677669529663687f  // 32^-0.5

__device__ __forceinline__ unsigned short f2b(float f) {
    __bf16 h = (__bf16)f;                       // RNE, packs to v_cvt_pk_bf16_f32
    return __builtin_bit_cast(unsigned short, h);
}
__device__ __forceinline__ float b2f(unsigned short h) {
    union { unsigned u; float f; } v; v.u = ((unsigned)h) << 16;
    return v.f;
}
__device__ __forceinline__ f32x4 mfma16(us8 a, us8 b, f32x4 c) {
    return __builtin_amdgcn_mfma_f32_16x16x32_bf16(
        __builtin_bit_cast(bf16x8, a), __builtin_bit_cast(bf16x8, b), c, 0, 0, 0);
}

// K=16 bf16 MFMA. A/B frag: 4 bf16, elem k=(lane>>4)*4+j. C/D standard.
#if __has_builtin(__builtin_amdgcn_mfma_f32_16x16x16bf16_1k)
__device__ __forceinline__ f32x4 mfma16k16(us4 a, us4 b, f32x4 c) {
    return __builtin_amdgcn_mfma_f32_16x16x16bf16_1k(
        __builtin_bit_cast(sh4, a), __builtin_bit_cast(sh4, b), c, 0, 0, 0);
}
#elif __has_builtin(__builtin_amdgcn_mfma_f32_16x16x16_bf16)
__device__ __forceinline__ f32x4 mfma16k16(us4 a, us4 b, f32x4 c) {
    return __builtin_amdgcn_mfma_f32_16x16x16_bf16(
        __builtin_bit_cast(bf16x4, a), __builtin_bit_cast(bf16x4, b), c, 0, 0, 0);
}
#else
__device__ __forceinline__ f32x4 mfma16k16(us4 a, us4 b, f32x4 c) {
    asm volatile("v_mfma_f32_16x16x16_bf16 %0, %1, %2, %0"
                 : "+v"(c) : "v"(a), "v"(b));
    return c;
}
#endif

__device__ __forceinline__ us8 lds_ld8(const unsigned short* base, int byteoff) {
    return *(const us8*)((const char*)base + byteoff);
}
__device__ __forceinline__ void lds_st8(unsigned short* base, int byteoff, us8 v) {
    *(us8*)((char*)base + byteoff) = v;
}

// ---------- weight transpose + bf16 convert:  dst[c][r] = src[r][c] ----------
__global__ void k_transpose(const float* __restrict__ src, unsigned short* __restrict__ dst,
                            int R, int C) {
    int idx = blockIdx.x * 256 + threadIdx.x;
    if (idx >= R * C) return;
    int r = idx / C, c = idx - r * C;
    dst[c * R + r] = f2b(src[idx]);
}

// ---------- pack MLP weights into per-ct 8KB fragment slices ----------
__global__ void k_pack_mlp(const float* __restrict__ fc1_w, const float* __restrict__ fc2_w,
                           unsigned short* __restrict__ wPack) {
    int gid = blockIdx.x * 256 + threadIdx.x;          // 131072 shorts total
    int ct = gid >> 12;                                 // 4096 shorts / slice
    int byte = (gid & 4095) * 2;
    float v;
    if (byte < 4096) {
        int kk = byte >> 10, rem = byte & 1023;
        int lane = rem >> 4, j = (rem & 15) >> 1;
        v = fc1_w[(size_t)(kk * 32 + (lane >> 4) * 8 + j) * 512 + ct * 16 + (lane & 15)];
    } else {
        int b2 = byte - 4096;
        int co = b2 >> 9, rem = b2 & 511;
        int lane = rem >> 3, j = (rem & 7) >> 1;
        v = fc2_w[(size_t)(ct * 16 + (lane >> 4) * 4 + j) * 128 + co * 16 + (lane & 15)];
    }
    wPack[gid] = f2b(v);
}

// =====================================================================
// K1: LN1 + roll + window-partition + QKV + attention + proj + residual
// (unchanged — measured at HBM roofline, ~46us)
// =====================================================================
__global__ __launch_bounds__(256, 3) void k_block1(
    const float* __restrict__ x,
    const float* __restrict__ ln1s, const float* __restrict__ ln1b,
    const unsigned short* __restrict__ qkvW, const float* __restrict__ qkvB,
    const float* __restrict__ relb,
    const unsigned short* __restrict__ projW, const float* __restrict__ projB,
    float* __restrict__ out)
{
    __shared__ unsigned short sm[4 * 6144];   // 48 KB
    __shared__ float sbias[196];
    const int tid = threadIdx.x;
    const int wave = tid >> 6, lane = tid & 63;
    const int g = lane >> 4, m16 = lane & 15;
    if (tid < 196) sbias[tid] = relb[tid];
    const int win0 = blockIdx.x * 4;
    const int winM = win0 + wave;
    const int bbM = winM >> 8, whM = (winM >> 4) & 15, wnM = winM & 15;

    // ---- phase A: LN1 + roll-gather -> A-tile [16][128] bf16, swizzled ----
    {
        float4 sc0 = *(const float4*)(ln1s + m16 * 8);
        float4 sc1 = *(const float4*)(ln1s + m16 * 8 + 4);
        float4 bi0 = *(const float4*)(ln1b + m16 * 8);
        float4 bi1 = *(const float4*)(ln1b + m16 * 8 + 4);
        #pragma unroll
        for (int it = 0; it < 4; ++it) {
            int tok = it * 4 + g;
            int ti = tok >> 2, tj = tok & 3;
            int hh = (whM * 4 + ti + 2) & 63, ww = (wnM * 4 + tj + 2) & 63;
            const float* xr = x + ((((size_t)bbM << 12) | (hh << 6) | ww) * 128) + m16 * 8;
            float4 v0 = *(const float4*)xr, v1 = *(const float4*)(xr + 4);
            float sum = v0.x + v0.y + v0.z + v0.w + v1.x + v1.y + v1.z + v1.w;
            float sq  = v0.x*v0.x + v0.y*v0.y + v0.z*v0.z + v0.w*v0.w
                      + v1.x*v1.x + v1.y*v1.y + v1.z*v1.z + v1.w*v1.w;
            #pragma unroll
            for (int m = 1; m < 16; m <<= 1) { sum += __shfl_xor(sum, m); sq += __shfl_xor(sq, m); }
            float mu = sum * 0.0078125f;
            float rstd = rsqrtf(sq * 0.0078125f - mu * mu + 1e-6f);
            us8 o;
            o[0] = f2b((v0.x - mu) * rstd * sc0.x + bi0.x);
            o[1] = f2b((v0.y - mu) * rstd * sc0.y + bi0.y);
            o[2] = f2b((v0.z - mu) * rstd * sc0.z + bi0.z);
            o[3] = f2b((v0.w - mu) * rstd * sc0.w + bi0.w);
            o[4] = f2b((v1.x - mu) * rstd * sc1.x + bi1.x);
            o[5] = f2b((v1.y - mu) * rstd * sc1.y + bi1.y);
            o[6] = f2b((v1.z - mu) * rstd * sc1.z + bi1.z);
            o[7] = f2b((v1.w - mu) * rstd * sc1.w + bi1.w);
            lds_st8(sm, wave * 12288 + tok * 256 + ((m16 * 16) ^ ((tok & 7) << 4)), o);
        }
    }
    __syncthreads();

    us8 afr[4][4];
    #pragma unroll
    for (int w = 0; w < 4; ++w)
        #pragma unroll
        for (int k = 0; k < 4; ++k)
            afr[w][k] = lds_ld8(sm, w * 12288 + m16 * 256 + ((k * 64 + g * 16) ^ ((m16 & 7) << 4)));
    __syncthreads();

    // ---- phase B: QKV GEMM, cols split by wave (96 each), 4-window B-reuse ----
    #pragma unroll
    for (int ct = 0; ct < 6; ++ct) {
        const int cb = wave * 96 + ct * 16;
        const unsigned short* bp = qkvW + (cb + m16) * 128 + g * 8;
        us8 b0 = *(const us8*)(bp);
        us8 b1 = *(const us8*)(bp + 32);
        us8 b2 = *(const us8*)(bp + 64);
        us8 b3 = *(const us8*)(bp + 96);
        f32x4 acc[4] = {{0.f,0.f,0.f,0.f},{0.f,0.f,0.f,0.f},{0.f,0.f,0.f,0.f},{0.f,0.f,0.f,0.f}};
        #pragma unroll
        for (int w = 0; w < 4; ++w) {
            acc[w] = mfma16(afr[w][0], b0, acc[w]);
            acc[w] = mfma16(afr[w][1], b1, acc[w]);
            acc[w] = mfma16(afr[w][2], b2, acc[w]);
            acc[w] = mfma16(afr[w][3], b3, acc[w]);
        }
        const int c = cb + m16;
        const float bias = qkvB[c];
        const int s = c >> 7;
        const int rem = c & 127, hq = rem >> 5, hd = rem & 31;
        #pragma unroll
        for (int w = 0; w < 4; ++w) {
            const int base = w * 12288;
            if (s == 2) {
                us4 pk;
                #pragma unroll
                for (int jj = 0; jj < 4; ++jj) pk[jj] = f2b(acc[w][jj] + bias);
                *(us4*)((char*)sm + base + 8192 + hq * 1024 + hd * 32 + g * 8) = pk;
            } else {
                #pragma unroll
                for (int jj = 0; jj < 4; ++jj) {
                    float v = acc[w][jj] + bias;
                    if (s == 0) v *= SCALE_Q;
                    int tok = g * 4 + jj;
                    *(unsigned short*)((char*)sm + base + s * 4096 + hq * 1024 + tok * 64 + hd * 2)
                        = f2b(v);
                }
            }
        }
    }
    __syncthreads();

    // ---- phase C: attention via MFMA (wave-local window) ----
    {
        const int base = wave * 12288;
        const int ti = m16 >> 2, tj = m16 & 3;
        const int hhq = whM * 4 + ti, wwq = wnM * 4 + tj;
        const int myid = (hhq < 60 ? 0 : (hhq < 62 ? 3 : 6)) + (wwq < 60 ? 0 : (wwq < 62 ? 1 : 2));
        f32x4 po[4][2];
        #pragma unroll
        for (int h = 0; h < 4; ++h) {
            us8 kf = lds_ld8(sm, base + 4096 + h * 1024 + m16 * 64 + g * 16);
            us8 qf = lds_ld8(sm, base +        h * 1024 + m16 * 64 + g * 16);
            f32x4 st = mfma16(kf, qf, (f32x4){0.f,0.f,0.f,0.f});
            float p[4];
            #pragma unroll
            for (int jj = 0; jj < 4; ++jj) {
                int kk = g * 4 + jj;
                int pi = kk >> 2, pj = kk & 3;
                int hhk = whM * 4 + pi, wwk = wnM * 4 + pj;
                int pid = (hhk < 60 ? 0 : (hhk < 62 ? 3 : 6)) + (wwk < 60 ? 0 : (wwk < 62 ? 1 : 2));
                float v = st[jj] + sbias[((ti - pi + 3) * 7 + (tj - pj + 3)) * 4 + h];
                p[jj] = (pid != myid) ? v - 100.f : v;
            }
            #pragma unroll
            for (int rep = 0; rep < 2; ++rep) {   // double softmax (faithful)
                float mx = fmaxf(fmaxf(p[0], p[1]), fmaxf(p[2], p[3]));
                mx = fmaxf(mx, __shfl_xor(mx, 16));
                mx = fmaxf(mx, __shfl_xor(mx, 32));
                float ssum = 0.f;
                #pragma unroll
                for (int jj = 0; jj < 4; ++jj) { p[jj] = __expf(p[jj] - mx); ssum += p[jj]; }
                ssum += __shfl_xor(ssum, 16);
                ssum += __shfl_xor(ssum, 32);
                float inv = 1.f / ssum;
                #pragma unroll
                for (int jj = 0; jj < 4; ++jj) p[jj] *= inv;
            }
            us4 pf;
            #pragma unroll
            for (int jj = 0; jj < 4; ++jj) pf[jj] = f2b(p[jj]);
            #pragma unroll
            for (int dh = 0; dh < 2; ++dh) {
                us4 vf = *(const us4*)((const char*)sm + base + 8192 + h * 1024
                                       + (dh * 16 + m16) * 32 + g * 8);
                po[h][dh] = mfma16k16(vf, pf, (f32x4){0.f,0.f,0.f,0.f});
            }
        }
        #pragma unroll
        for (int h = 0; h < 4; ++h)
            #pragma unroll
            for (int dh = 0; dh < 2; ++dh) {
                us4 pk;
                #pragma unroll
                for (int jj = 0; jj < 4; ++jj) pk[jj] = f2b(po[h][dh][jj]);
                *(us4*)((char*)sm + base + m16 * 256
                        + ((h * 64 + dh * 32 + g * 8) ^ ((m16 & 7) << 4))) = pk;
            }
    }
    __syncthreads();

    // ---- phase D: proj (cols split by wave: 32 each) + unroll-scatter + residual ----
    {
        us8 cfr[4][4];
        #pragma unroll
        for (int w = 0; w < 4; ++w)
            #pragma unroll
            for (int k = 0; k < 4; ++k)
                cfr[w][k] = lds_ld8(sm, w * 12288 + m16 * 256 + ((k * 64 + g * 16) ^ ((m16 & 7) << 4)));
        #pragma unroll
        for (int ct = 0; ct < 2; ++ct) {
            const int c = wave * 32 + ct * 16 + m16;
            const unsigned short* bp = projW + c * 128 + g * 8;
            us8 b0 = *(const us8*)(bp);
            us8 b1 = *(const us8*)(bp + 32);
            us8 b2 = *(const us8*)(bp + 64);
            us8 b3 = *(const us8*)(bp + 96);
            const float pb = projB[c];
            #pragma unroll
            for (int w = 0; w < 4; ++w) {
                f32x4 acc = {0.f, 0.f, 0.f, 0.f};
                acc = mfma16(cfr[w][0], b0, acc);
                acc = mfma16(cfr[w][1], b1, acc);
                acc = mfma16(cfr[w][2], b2, acc);
                acc = mfma16(cfr[w][3], b3, acc);
                const int winw = win0 + w;
                const int bb = winw >> 8, wh = (winw >> 4) & 15, wn = winw & 15;
                #pragma unroll
                for (int jj = 0; jj < 4; ++jj) {
                    int tok = g * 4 + jj;
                    int hh3 = (wh * 4 + (tok >> 2) + 2) & 63;
                    int ww3 = (wn * 4 + (tok & 3) + 2) & 63;
                    size_t t = (((size_t)bb << 12) | (hh3 << 6) | ww3);
                    out[t * 128 + c] = acc[jj] + pb + x[t * 128 + c];
                }
            }
        }
    }
}

// =====================================================================
// K2 v6: LN2 + FC1 + GELU + FC2 + residual. Hidden in registers.
// 8 waves x 16 rows = 128 rows/block (512 thr). Small per-wave state
// (accO=32 AGPR, bx=16 VGPR) -> 4 waves/SIMD. Weights double-buffered
// in LDS, staged by ONE global_load_lds per thread per iter.
// =====================================================================
__global__ __launch_bounds__(512, 4) void k_block2(
    float* __restrict__ out,
    const float* __restrict__ ln2s, const float* __restrict__ ln2b,
    const unsigned short* __restrict__ wPack,
    const float* __restrict__ fc1B, const float* __restrict__ fc2B)
{
    __shared__ unsigned short scratch[8][2048];   // 4KB per wave (16 rows x 256B)
    __shared__ unsigned short wbuf[2][4096];      // 2 x 8KB weight staging
    const int tid = threadIdx.x;
    const int wave = tid >> 6, lane = tid & 63;
    const int g = lane >> 4, m16 = lane & 15;
    const size_t r0 = (size_t)blockIdx.x * 128;

    // ---- stage slice 0 (512 threads x 16B = 8KB) ----
    {
        const unsigned short* src = wPack + tid * 8;
        unsigned short* dst = &wbuf[0][wave * 512];
#if __has_builtin(__builtin_amdgcn_global_load_lds)
        __builtin_amdgcn_global_load_lds(
            (const __attribute__((address_space(1))) void*)src,
            (__attribute__((address_space(3))) void*)dst, 16, 0, 0);
#else
        *(us8*)(dst + lane * 8) = *(const us8*)src;
#endif
    }

    // ---- LN2 on this wave's 16 rows -> wave-private scratch (no barrier) ----
    {
        float4 sc0 = *(const float4*)(ln2s + m16 * 8);
        float4 sc1 = *(const float4*)(ln2s + m16 * 8 + 4);
        float4 bi0 = *(const float4*)(ln2b + m16 * 8);
        float4 bi1 = *(const float4*)(ln2b + m16 * 8 + 4);
        #pragma unroll
        for (int it = 0; it < 4; ++it) {
            int lr = it * 4 + g;                             // 0..15 local
            const float* xr = out + (r0 + wave * 16 + lr) * 128 + m16 * 8;
            float4 v0 = *(const float4*)xr, v1 = *(const float4*)(xr + 4);
            float sum = v0.x + v0.y + v0.z + v0.w + v1.x + v1.y + v1.z + v1.w;
            float sq  = v0.x*v0.x + v0.y*v0.y + v0.z*v0.z + v0.w*v0.w
                      + v1.x*v1.x + v1.y*v1.y + v1.z*v1.z + v1.w*v1.w;
            #pragma unroll
            for (int m = 1; m < 16; m <<= 1) { sum += __shfl_xor(sum, m); sq += __shfl_xor(sq, m); }
            float mu = sum * 0.0078125f;
            float rstd = rsqrtf(sq * 0.0078125f - mu * mu + 1e-6f);
            us8 o;
            o[0] = f2b((v0.x - mu) * rstd * sc0.x + bi0.x);
            o[1] = f2b((v0.y - mu) * rstd * sc0.y + bi0.y);
            o[2] = f2b((v0.z - mu) * rstd * sc0.z + bi0.z);
            o[3] = f2b((v0.w - mu) * rstd * sc0.w + bi0.w);
            o[4] = f2b((v1.x - mu) * rstd * sc1.x + bi1.x);
            o[5] = f2b((v1.y - mu) * rstd * sc1.y + bi1.y);
            o[6] = f2b((v1.z - mu) * rstd * sc1.z + bi1.z);
            o[7] = f2b((v1.w - mu) * rstd * sc1.w + bi1.w);
            lds_st8(&scratch[wave][0], lr * 256 + ((m16 * 16) ^ ((lr & 7) << 4)), o);
        }
    }

    // ---- hoist x B-frags (16 rows, K=128 -> 4 frags, 16 VGPR) ----
    us8 bx[4];
    #pragma unroll
    for (int kk = 0; kk < 4; ++kk)
        bx[kk] = lds_ld8(&scratch[wave][0],
                         m16 * 256 + ((kk * 64 + g * 16) ^ ((m16 & 7) << 4)));
    __syncthreads();   // slice-0 staged + everyone ready

    f32x4 accO[8];
    #pragma unroll
    for (int co = 0; co < 8; ++co) accO[co] = (f32x4){0.f, 0.f, 0.f, 0.f};

    for (int ct = 0; ct < 32; ++ct) {
        // stage next slice into the other buffer (issue-early)
        if (ct < 31) {
            const unsigned short* src = wPack + (ct + 1) * 4096 + tid * 8;
            unsigned short* dst = &wbuf[(ct + 1) & 1][wave * 512];
#if __has_builtin(__builtin_amdgcn_global_load_lds)
            __builtin_amdgcn_global_load_lds(
                (const __attribute__((address_space(1))) void*)src,
                (__attribute__((address_space(3))) void*)dst, 16, 0, 0);
#else
            *(us8*)(dst + lane * 8) = *(const us8*)src;
#endif
        }
        const char* wb = (const char*)&wbuf[ct & 1][0];
        // FC1^T: h[jj] = hid[row = wave*16+m16][col = ct*16 + g*4 + jj]
        us8 aw0 = *(const us8*)(wb + 0 * 1024 + lane * 16);
        us8 aw1 = *(const us8*)(wb + 1 * 1024 + lane * 16);
        us8 aw2 = *(const us8*)(wb + 2 * 1024 + lane * 16);
        us8 aw3 = *(const us8*)(wb + 3 * 1024 + lane * 16);
        f32x4 h = {0.f, 0.f, 0.f, 0.f};
        h = mfma16(aw0, bx[0], h);
        h = mfma16(aw1, bx[1], h);
        h = mfma16(aw2, bx[2], h);
        h = mfma16(aw3, bx[3], h);
        float4 b1v = *(const float4*)(fc1B + ct * 16 + g * 4);
        us4 pa;
        #pragma unroll
        for (int jj = 0; jj < 4; ++jj) {
            float v = h[jj] + ((const float*)&b1v)[jj];
            float z = v + 0.044715f * v * v * v;
            float e = __builtin_amdgcn_exp2f(-2.3022082f * z);   // exp(-1.59577 z)
            pa[jj] = f2b(v * __builtin_amdgcn_rcpf(1.f + e));
        }
        // FC2 partial-K accumulate (K=16 MFMA), B-frags read after FC1 (live-range)
        #pragma unroll
        for (int co = 0; co < 8; ++co) {
            us4 bw = *(const us4*)(wb + 4096 + co * 512 + lane * 8);
            accO[co] = mfma16k16(pa, bw, accO[co]);
        }
        __syncthreads();
    }

    // ---- epilogue: bias + residual, in-place fp32 ----
    #pragma unroll
    for (int co = 0; co < 8; ++co) {
        int col = co * 16 + m16;
        float b2v = fc2B[col];
        #pragma unroll
        for (int jj = 0; jj < 4; ++jj) {
            size_t row = r0 + wave * 16 + g * 4 + jj;
            float* op = out + row * 128 + col;
            *op = accO[co][jj] + b2v + *op;
        }
    }
}

// ---------- launch ----------
extern "C" void kernel_launch(void* const* d_in, const int* in_sizes, int n_in,
                              void* d_out, int out_size, void* d_ws, size_t ws_size,
                              hipStream_t stream) {
    const float* x        = (const float*)d_in[0];
    const float* ln1_s    = (const float*)d_in[1];
    const float* ln1_b    = (const float*)d_in[2];
    const float* qkv_w    = (const float*)d_in[3];
    const float* qkv_b    = (const float*)d_in[4];
    const float* rel_bias = (const float*)d_in[5];
    const float* proj_w   = (const float*)d_in[6];
    const float* proj_b   = (const float*)d_in[7];
    const float* ln2_s    = (const float*)d_in[8];
    const float* ln2_b    = (const float*)d_in[9];
    const float* fc1_w    = (const float*)d_in[10];
    const float* fc1_b    = (const float*)d_in[11];
    const float* fc2_w    = (const float*)d_in[12];
    const float* fc2_b    = (const float*)d_in[13];
    float* out = (float*)d_out;
    char* ws = (char*)d_ws;

    unsigned short* qkv_wt  = (unsigned short*)(ws);             // 384x128 bf16 (96KB)
    unsigned short* proj_wt = (unsigned short*)(ws + 98304);     // 128x128 (32KB)
    unsigned short* wpack   = (unsigned short*)(ws + 131072);    // 32x8KB = 256KB

    k_transpose<<<192, 256, 0, stream>>>(qkv_w, qkv_wt, 128, 384);
    k_transpose<<<64,  256, 0, stream>>>(proj_w, proj_wt, 128, 128);
    k_pack_mlp<<<512, 256, 0, stream>>>(fc1_w, fc2_w, wpack);

    k_block1<<<4096, 256, 0, stream>>>(x, ln1_s, ln1_b, qkv_wt, qkv_b, rel_bias,
                                       proj_wt, proj_b, out);
    k_block2<<<2048, 512, 0, stream>>>(out, ln2_s, ln2_b, wpack, fc1_b, fc2_b);
}

// Round 9
// 233.111 us; speedup vs baseline: 3.0846x; 1.0867x over previous
//
#include <hip/hip_runtime.h>

typedef __bf16 bf16x8 __attribute__((ext_vector_type(8)));
typedef __bf16 bf16x4 __attribute__((ext_vector_type(4)));
typedef float f32x4 __attribute__((ext_vector_type(4)));
typedef unsigned short us8 __attribute__((ext_vector_type(8)));
typedef unsigned short us4 __attribute__((ext_vector_type(4)));
typedef short sh4 __attribute__((ext_vector_type(4)));

#define SCALE_Q 0.17677669529663687f  // 32^-0.5

__device__ __forceinline__ unsigned short f2b(float f) {
    __bf16 h = (__bf16)f;
    return __builtin_bit_cast(unsigned short, h);
}
__device__ __forceinline__ float b2f(unsigned short h) {
    union { unsigned u; float f; } v; v.u = ((unsigned)h) << 16;
    return v.f;
}
__device__ __forceinline__ f32x4 mfma16(us8 a, us8 b, f32x4 c) {
    return __builtin_amdgcn_mfma_f32_16x16x32_bf16(
        __builtin_bit_cast(bf16x8, a), __builtin_bit_cast(bf16x8, b), c, 0, 0, 0);
}

#if __has_builtin(__builtin_amdgcn_mfma_f32_16x16x16bf16_1k)
__device__ __forceinline__ f32x4 mfma16k16(us4 a, us4 b, f32x4 c) {
    return __builtin_amdgcn_mfma_f32_16x16x16bf16_1k(
        __builtin_bit_cast(sh4, a), __builtin_bit_cast(sh4, b), c, 0, 0, 0);
}
#elif __has_builtin(__builtin_amdgcn_mfma_f32_16x16x16_bf16)
__device__ __forceinline__ f32x4 mfma16k16(us4 a, us4 b, f32x4 c) {
    return __builtin_amdgcn_mfma_f32_16x16x16_bf16(
        __builtin_bit_cast(bf16x4, a), __builtin_bit_cast(bf16x4, b), c, 0, 0, 0);
}
#else
__device__ __forceinline__ f32x4 mfma16k16(us4 a, us4 b, f32x4 c) {
    asm volatile("v_mfma_f32_16x16x16_bf16 %0, %1, %2, %0"
                 : "+v"(c) : "v"(a), "v"(b));
    return c;
}
#endif

__device__ __forceinline__ us8 lds_ld8(const unsigned short* base, int byteoff) {
    return *(const us8*)((const char*)base + byteoff);
}
__device__ __forceinline__ void lds_st8(unsigned short* base, int byteoff, us8 v) {
    *(us8*)((char*)base + byteoff) = v;
}

// ---------- pack qkv weights into per-(wave,ct) fragment blocks, fold SCALE_Q ----------
// blk = (w*6+ct)*4+kk (0..95), 512 shorts each:
//   qkvWp[blk*512 + lane*8 + j] = qkv_w[(kk*32+(lane>>4)*8+j)*384 + (w*96+ct*16+(lane&15))] * (col<128?SCALE_Q:1)
__global__ void k_pack_qkvw(const float* __restrict__ qkv_w, unsigned short* __restrict__ dst) {
    int gid = blockIdx.x * 256 + threadIdx.x;          // 49152
    int blk = gid >> 9, rem = gid & 511;
    int lane = rem >> 3, j = rem & 7;
    int w = blk / 24, r1 = blk % 24, ct = r1 >> 2, kk = r1 & 3;
    int col = w * 96 + ct * 16 + (lane & 15);
    int k = kk * 32 + (lane >> 4) * 8 + j;
    float v = qkv_w[k * 384 + col];
    if (col < 128) v *= SCALE_Q;
    dst[gid] = f2b(v);
}
// scaled qkv bias
__global__ void k_scale_qkvb(const float* __restrict__ qkv_b, float* __restrict__ dst) {
    int i = blockIdx.x * 256 + threadIdx.x;
    if (i < 384) dst[i] = qkv_b[i] * (i < 128 ? SCALE_Q : 1.f);
}
// ---------- pack proj weights: blk=(w*2+ct)*4+kk (0..31) ----------
__global__ void k_pack_projw(const float* __restrict__ proj_w, unsigned short* __restrict__ dst) {
    int gid = blockIdx.x * 256 + threadIdx.x;          // 16384
    int blk = gid >> 9, rem = gid & 511;
    int lane = rem >> 3, j = rem & 7;
    int w = blk >> 3, r1 = blk & 7, ct = r1 >> 2, kk = r1 & 3;
    int col = w * 32 + ct * 16 + (lane & 15);
    int k = kk * 32 + (lane >> 4) * 8 + j;
    dst[gid] = f2b(proj_w[k * 128 + col]);
}

// ---------- pack MLP weights into per-ct 8KB fragment slices (unchanged) ----------
__global__ void k_pack_mlp(const float* __restrict__ fc1_w, const float* __restrict__ fc2_w,
                           unsigned short* __restrict__ wPack) {
    int gid = blockIdx.x * 256 + threadIdx.x;
    int ct = gid >> 12;
    int byte = (gid & 4095) * 2;
    float v;
    if (byte < 4096) {
        int kk = byte >> 10, rem = byte & 1023;
        int lane = rem >> 4, j = (rem & 15) >> 1;
        v = fc1_w[(size_t)(kk * 32 + (lane >> 4) * 8 + j) * 512 + ct * 16 + (lane & 15)];
    } else {
        int b2 = byte - 4096;
        int co = b2 >> 9, rem = b2 & 511;
        int lane = rem >> 3, j = (rem & 7) >> 1;
        v = fc2_w[(size_t)(ct * 16 + (lane >> 4) * 4 + j) * 128 + co * 16 + (lane & 15)];
    }
    wPack[gid] = f2b(v);
}

// =====================================================================
// K1 v2: LN1 + roll + window-partition + QKV + attention + proj + residual
// Changes vs r8: (a) swizzled Q/K/V LDS layouts -> 2-way max bank
// conflicts on attention fragment reads; (b) packed fragment weights ->
// fully coalesced global B-loads; (c) SCALE_Q folded into weights/bias.
// Q/K element (tok,hd) at: tok*64 + ((hd>>3)^((tok>>1)&3))*16 + (hd&7)*2
// V us4 (hd, tokquad g) at: hd*32 + ((g^((hd>>2)&3))<<3)
// =====================================================================
__global__ __launch_bounds__(256, 3) void k_block1(
    const float* __restrict__ x,
    const float* __restrict__ ln1s, const float* __restrict__ ln1b,
    const unsigned short* __restrict__ qkvWp, const float* __restrict__ qkvBs,
    const float* __restrict__ relb,
    const unsigned short* __restrict__ projWp, const float* __restrict__ projB,
    float* __restrict__ out)
{
    __shared__ unsigned short sm[4 * 6144];   // 48 KB
    __shared__ float sbias[196];
    const int tid = threadIdx.x;
    const int wave = tid >> 6, lane = tid & 63;
    const int g = lane >> 4, m16 = lane & 15;
    if (tid < 196) sbias[tid] = relb[tid];
    const int win0 = blockIdx.x * 4;
    const int winM = win0 + wave;
    const int bbM = winM >> 8, whM = (winM >> 4) & 15, wnM = winM & 15;

    // ---- phase A: LN1 + roll-gather -> A-tile [16][256B], XOR-swizzled ----
    {
        float4 sc0 = *(const float4*)(ln1s + m16 * 8);
        float4 sc1 = *(const float4*)(ln1s + m16 * 8 + 4);
        float4 bi0 = *(const float4*)(ln1b + m16 * 8);
        float4 bi1 = *(const float4*)(ln1b + m16 * 8 + 4);
        #pragma unroll
        for (int it = 0; it < 4; ++it) {
            int tok = it * 4 + g;
            int ti = tok >> 2, tj = tok & 3;
            int hh = (whM * 4 + ti + 2) & 63, ww = (wnM * 4 + tj + 2) & 63;
            const float* xr = x + ((((size_t)bbM << 12) | (hh << 6) | ww) * 128) + m16 * 8;
            float4 v0 = *(const float4*)xr, v1 = *(const float4*)(xr + 4);
            float sum = v0.x + v0.y + v0.z + v0.w + v1.x + v1.y + v1.z + v1.w;
            float sq  = v0.x*v0.x + v0.y*v0.y + v0.z*v0.z + v0.w*v0.w
                      + v1.x*v1.x + v1.y*v1.y + v1.z*v1.z + v1.w*v1.w;
            #pragma unroll
            for (int m = 1; m < 16; m <<= 1) { sum += __shfl_xor(sum, m); sq += __shfl_xor(sq, m); }
            float mu = sum * 0.0078125f;
            float rstd = rsqrtf(sq * 0.0078125f - mu * mu + 1e-6f);
            us8 o;
            o[0] = f2b((v0.x - mu) * rstd * sc0.x + bi0.x);
            o[1] = f2b((v0.y - mu) * rstd * sc0.y + bi0.y);
            o[2] = f2b((v0.z - mu) * rstd * sc0.z + bi0.z);
            o[3] = f2b((v0.w - mu) * rstd * sc0.w + bi0.w);
            o[4] = f2b((v1.x - mu) * rstd * sc1.x + bi1.x);
            o[5] = f2b((v1.y - mu) * rstd * sc1.y + bi1.y);
            o[6] = f2b((v1.z - mu) * rstd * sc1.z + bi1.z);
            o[7] = f2b((v1.w - mu) * rstd * sc1.w + bi1.w);
            lds_st8(sm, wave * 12288 + tok * 256 + ((m16 * 16) ^ ((tok & 7) << 4)), o);
        }
    }
    __syncthreads();

    us8 afr[4][4];
    #pragma unroll
    for (int w = 0; w < 4; ++w)
        #pragma unroll
        for (int k = 0; k < 4; ++k)
            afr[w][k] = lds_ld8(sm, w * 12288 + m16 * 256 + ((k * 64 + g * 16) ^ ((m16 & 7) << 4)));
    __syncthreads();

    // ---- phase B: QKV GEMM, cols split by wave, packed coalesced B-frags ----
    #pragma unroll
    for (int ct = 0; ct < 6; ++ct) {
        const unsigned short* bp = qkvWp + (size_t)((wave * 6 + ct) * 4) * 512 + lane * 8;
        us8 b0 = *(const us8*)(bp);
        us8 b1 = *(const us8*)(bp + 512);
        us8 b2 = *(const us8*)(bp + 1024);
        us8 b3 = *(const us8*)(bp + 1536);
        f32x4 acc[4] = {{0.f,0.f,0.f,0.f},{0.f,0.f,0.f,0.f},{0.f,0.f,0.f,0.f},{0.f,0.f,0.f,0.f}};
        #pragma unroll
        for (int w = 0; w < 4; ++w) {
            acc[w] = mfma16(afr[w][0], b0, acc[w]);
            acc[w] = mfma16(afr[w][1], b1, acc[w]);
            acc[w] = mfma16(afr[w][2], b2, acc[w]);
            acc[w] = mfma16(afr[w][3], b3, acc[w]);
        }
        const int c = wave * 96 + ct * 16 + m16;
        const float bias = qkvBs[c];
        const int s = c >> 7;                 // wave-uniform per ct
        const int rem = c & 127, hq = rem >> 5, hd = rem & 31;
        #pragma unroll
        for (int w = 0; w < 4; ++w) {
            const int base = w * 12288;
            if (s == 2) {                     // V: [hd][tok] swizzled, packed b64
                us4 pk;
                #pragma unroll
                for (int jj = 0; jj < 4; ++jj) pk[jj] = f2b(acc[w][jj] + bias);
                *(us4*)((char*)sm + base + 8192 + hq * 1024 + hd * 32
                        + ((g ^ ((hd >> 2) & 3)) << 3)) = pk;
            } else {                          // Q/K: [tok][hd] chunk-swizzled
                #pragma unroll
                for (int jj = 0; jj < 4; ++jj) {
                    int tok = g * 4 + jj;
                    int chunk = (hd >> 3) ^ ((tok >> 1) & 3);
                    *(unsigned short*)((char*)sm + base + s * 4096 + hq * 1024
                                       + tok * 64 + chunk * 16 + (hd & 7) * 2)
                        = f2b(acc[w][jj] + bias);
                }
            }
        }
    }
    __syncthreads();

    // ---- phase C: attention via MFMA (wave-local window) ----
    {
        const int base = wave * 12288;
        const int ti = m16 >> 2, tj = m16 & 3;
        const int hhq = whM * 4 + ti, wwq = wnM * 4 + tj;
        const int myid = (hhq < 60 ? 0 : (hhq < 62 ? 3 : 6)) + (wwq < 60 ? 0 : (wwq < 62 ? 1 : 2));
        const int qkswz = (g ^ ((m16 >> 1) & 3)) * 16;       // chunk swizzle for row m16
        const int vswz  = (g ^ ((m16 >> 2) & 3)) << 3;       // quad swizzle for V rows
        f32x4 po[4][2];
        #pragma unroll
        for (int h = 0; h < 4; ++h) {
            us8 kf = lds_ld8(sm, base + 4096 + h * 1024 + m16 * 64 + qkswz);
            us8 qf = lds_ld8(sm, base +        h * 1024 + m16 * 64 + qkswz);
            f32x4 st = mfma16(kf, qf, (f32x4){0.f,0.f,0.f,0.f});
            float p[4];
            #pragma unroll
            for (int jj = 0; jj < 4; ++jj) {
                int kk = g * 4 + jj;
                int pi = kk >> 2, pj = kk & 3;
                int hhk = whM * 4 + pi, wwk = wnM * 4 + pj;
                int pid = (hhk < 60 ? 0 : (hhk < 62 ? 3 : 6)) + (wwk < 60 ? 0 : (wwk < 62 ? 1 : 2));
                float v = st[jj] + sbias[((ti - pi + 3) * 7 + (tj - pj + 3)) * 4 + h];
                p[jj] = (pid != myid) ? v - 100.f : v;
            }
            #pragma unroll
            for (int rep = 0; rep < 2; ++rep) {   // double softmax (faithful)
                float mx = fmaxf(fmaxf(p[0], p[1]), fmaxf(p[2], p[3]));
                mx = fmaxf(mx, __shfl_xor(mx, 16));
                mx = fmaxf(mx, __shfl_xor(mx, 32));
                float ssum = 0.f;
                #pragma unroll
                for (int jj = 0; jj < 4; ++jj) { p[jj] = __expf(p[jj] - mx); ssum += p[jj]; }
                ssum += __shfl_xor(ssum, 16);
                ssum += __shfl_xor(ssum, 32);
                float inv = 1.f / ssum;
                #pragma unroll
                for (int jj = 0; jj < 4; ++jj) p[jj] *= inv;
            }
            us4 pf;
            #pragma unroll
            for (int jj = 0; jj < 4; ++jj) pf[jj] = f2b(p[jj]);
            #pragma unroll
            for (int dh = 0; dh < 2; ++dh) {
                us4 vf = *(const us4*)((const char*)sm + base + 8192 + h * 1024
                                       + (dh * 16 + m16) * 32 + vswz);
                po[h][dh] = mfma16k16(vf, pf, (f32x4){0.f,0.f,0.f,0.f});
            }
        }
        // write sO (aliases Q region): [16 q][256B] swizzled
        #pragma unroll
        for (int h = 0; h < 4; ++h)
            #pragma unroll
            for (int dh = 0; dh < 2; ++dh) {
                us4 pk;
                #pragma unroll
                for (int jj = 0; jj < 4; ++jj) pk[jj] = f2b(po[h][dh][jj]);
                *(us4*)((char*)sm + base + m16 * 256
                        + ((h * 64 + dh * 32 + g * 8) ^ ((m16 & 7) << 4))) = pk;
            }
    }
    __syncthreads();

    // ---- phase D: proj (cols split by wave) + unroll-scatter + residual ----
    {
        us8 cfr[4][4];
        #pragma unroll
        for (int w = 0; w < 4; ++w)
            #pragma unroll
            for (int k = 0; k < 4; ++k)
                cfr[w][k] = lds_ld8(sm, w * 12288 + m16 * 256 + ((k * 64 + g * 16) ^ ((m16 & 7) << 4)));
        #pragma unroll
        for (int ct = 0; ct < 2; ++ct) {
            const unsigned short* bp = projWp + (size_t)((wave * 2 + ct) * 4) * 512 + lane * 8;
            us8 b0 = *(const us8*)(bp);
            us8 b1 = *(const us8*)(bp + 512);
            us8 b2 = *(const us8*)(bp + 1024);
            us8 b3 = *(const us8*)(bp + 1536);
            const int c = wave * 32 + ct * 16 + m16;
            const float pb = projB[c];
            #pragma unroll
            for (int w = 0; w < 4; ++w) {
                f32x4 acc = {0.f, 0.f, 0.f, 0.f};
                acc = mfma16(cfr[w][0], b0, acc);
                acc = mfma16(cfr[w][1], b1, acc);
                acc = mfma16(cfr[w][2], b2, acc);
                acc = mfma16(cfr[w][3], b3, acc);
                const int winw = win0 + w;
                const int bb = winw >> 8, wh = (winw >> 4) & 15, wn = winw & 15;
                #pragma unroll
                for (int jj = 0; jj < 4; ++jj) {
                    int tok = g * 4 + jj;
                    int hh3 = (wh * 4 + (tok >> 2) + 2) & 63;
                    int ww3 = (wn * 4 + (tok & 3) + 2) & 63;
                    size_t t = (((size_t)bb << 12) | (hh3 << 6) | ww3);
                    out[t * 128 + c] = acc[jj] + pb + x[t * 128 + c];
                }
            }
        }
    }
}

// =====================================================================
// K2 v6 (unchanged from r8): LN2 + FC1 + GELU + FC2 + residual.
// =====================================================================
__global__ __launch_bounds__(512, 4) void k_block2(
    float* __restrict__ out,
    const float* __restrict__ ln2s, const float* __restrict__ ln2b,
    const unsigned short* __restrict__ wPack,
    const float* __restrict__ fc1B, const float* __restrict__ fc2B)
{
    __shared__ unsigned short scratch[8][2048];
    __shared__ unsigned short wbuf[2][4096];
    const int tid = threadIdx.x;
    const int wave = tid >> 6, lane = tid & 63;
    const int g = lane >> 4, m16 = lane & 15;
    const size_t r0 = (size_t)blockIdx.x * 128;

    {
        const unsigned short* src = wPack + tid * 8;
        unsigned short* dst = &wbuf[0][wave * 512];
#if __has_builtin(__builtin_amdgcn_global_load_lds)
        __builtin_amdgcn_global_load_lds(
            (const __attribute__((address_space(1))) void*)src,
            (__attribute__((address_space(3))) void*)dst, 16, 0, 0);
#else
        *(us8*)(dst + lane * 8) = *(const us8*)src;
#endif
    }

    {
        float4 sc0 = *(const float4*)(ln2s + m16 * 8);
        float4 sc1 = *(const float4*)(ln2s + m16 * 8 + 4);
        float4 bi0 = *(const float4*)(ln2b + m16 * 8);
        float4 bi1 = *(const float4*)(ln2b + m16 * 8 + 4);
        #pragma unroll
        for (int it = 0; it < 4; ++it) {
            int lr = it * 4 + g;
            const float* xr = out + (r0 + wave * 16 + lr) * 128 + m16 * 8;
            float4 v0 = *(const float4*)xr, v1 = *(const float4*)(xr + 4);
            float sum = v0.x + v0.y + v0.z + v0.w + v1.x + v1.y + v1.z + v1.w;
            float sq  = v0.x*v0.x + v0.y*v0.y + v0.z*v0.z + v0.w*v0.w
                      + v1.x*v1.x + v1.y*v1.y + v1.z*v1.z + v1.w*v1.w;
            #pragma unroll
            for (int m = 1; m < 16; m <<= 1) { sum += __shfl_xor(sum, m); sq += __shfl_xor(sq, m); }
            float mu = sum * 0.0078125f;
            float rstd = rsqrtf(sq * 0.0078125f - mu * mu + 1e-6f);
            us8 o;
            o[0] = f2b((v0.x - mu) * rstd * sc0.x + bi0.x);
            o[1] = f2b((v0.y - mu) * rstd * sc0.y + bi0.y);
            o[2] = f2b((v0.z - mu) * rstd * sc0.z + bi0.z);
            o[3] = f2b((v0.w - mu) * rstd * sc0.w + bi0.w);
            o[4] = f2b((v1.x - mu) * rstd * sc1.x + bi1.x);
            o[5] = f2b((v1.y - mu) * rstd * sc1.y + bi1.y);
            o[6] = f2b((v1.z - mu) * rstd * sc1.z + bi1.z);
            o[7] = f2b((v1.w - mu) * rstd * sc1.w + bi1.w);
            lds_st8(&scratch[wave][0], lr * 256 + ((m16 * 16) ^ ((lr & 7) << 4)), o);
        }
    }

    us8 bx[4];
    #pragma unroll
    for (int kk = 0; kk < 4; ++kk)
        bx[kk] = lds_ld8(&scratch[wave][0],
                         m16 * 256 + ((kk * 64 + g * 16) ^ ((m16 & 7) << 4)));
    __syncthreads();

    f32x4 accO[8];
    #pragma unroll
    for (int co = 0; co < 8; ++co) accO[co] = (f32x4){0.f, 0.f, 0.f, 0.f};

    for (int ct = 0; ct < 32; ++ct) {
        if (ct < 31) {
            const unsigned short* src = wPack + (ct + 1) * 4096 + tid * 8;
            unsigned short* dst = &wbuf[(ct + 1) & 1][wave * 512];
#if __has_builtin(__builtin_amdgcn_global_load_lds)
            __builtin_amdgcn_global_load_lds(
                (const __attribute__((address_space(1))) void*)src,
                (__attribute__((address_space(3))) void*)dst, 16, 0, 0);
#else
            *(us8*)(dst + lane * 8) = *(const us8*)src;
#endif
        }
        const char* wb = (const char*)&wbuf[ct & 1][0];
        us8 aw0 = *(const us8*)(wb + 0 * 1024 + lane * 16);
        us8 aw1 = *(const us8*)(wb + 1 * 1024 + lane * 16);
        us8 aw2 = *(const us8*)(wb + 2 * 1024 + lane * 16);
        us8 aw3 = *(const us8*)(wb + 3 * 1024 + lane * 16);
        f32x4 h = {0.f, 0.f, 0.f, 0.f};
        h = mfma16(aw0, bx[0], h);
        h = mfma16(aw1, bx[1], h);
        h = mfma16(aw2, bx[2], h);
        h = mfma16(aw3, bx[3], h);
        float4 b1v = *(const float4*)(fc1B + ct * 16 + g * 4);
        us4 pa;
        #pragma unroll
        for (int jj = 0; jj < 4; ++jj) {
            float v = h[jj] + ((const float*)&b1v)[jj];
            float z = v + 0.044715f * v * v * v;
            float e = __builtin_amdgcn_exp2f(-2.3022082f * z);
            pa[jj] = f2b(v * __builtin_amdgcn_rcpf(1.f + e));
        }
        #pragma unroll
        for (int co = 0; co < 8; ++co) {
            us4 bw = *(const us4*)(wb + 4096 + co * 512 + lane * 8);
            accO[co] = mfma16k16(pa, bw, accO[co]);
        }
        __syncthreads();
    }

    #pragma unroll
    for (int co = 0; co < 8; ++co) {
        int col = co * 16 + m16;
        float b2v = fc2B[col];
        #pragma unroll
        for (int jj = 0; jj < 4; ++jj) {
            size_t row = r0 + wave * 16 + g * 4 + jj;
            float* op = out + row * 128 + col;
            *op = accO[co][jj] + b2v + *op;
        }
    }
}

// ---------- launch ----------
extern "C" void kernel_launch(void* const* d_in, const int* in_sizes, int n_in,
                              void* d_out, int out_size, void* d_ws, size_t ws_size,
                              hipStream_t stream) {
    const float* x        = (const float*)d_in[0];
    const float* ln1_s    = (const float*)d_in[1];
    const float* ln1_b    = (const float*)d_in[2];
    const float* qkv_w    = (const float*)d_in[3];
    const float* qkv_b    = (const float*)d_in[4];
    const float* rel_bias = (const float*)d_in[5];
    const float* proj_w   = (const float*)d_in[6];
    const float* proj_b   = (const float*)d_in[7];
    const float* ln2_s    = (const float*)d_in[8];
    const float* ln2_b    = (const float*)d_in[9];
    const float* fc1_w    = (const float*)d_in[10];
    const float* fc1_b    = (const float*)d_in[11];
    const float* fc2_w    = (const float*)d_in[12];
    const float* fc2_b    = (const float*)d_in[13];
    float* out = (float*)d_out;
    char* ws = (char*)d_ws;

    unsigned short* qkv_wp  = (unsigned short*)(ws);             // 96KB packed qkv frags
    unsigned short* proj_wp = (unsigned short*)(ws + 98304);     // 32KB packed proj frags
    unsigned short* wpack   = (unsigned short*)(ws + 131072);    // 256KB packed MLP
    float*          qkv_bs  = (float*)(ws + 393216);             // 1.5KB scaled qkv bias

    k_pack_qkvw<<<192, 256, 0, stream>>>(qkv_w, qkv_wp);
    k_scale_qkvb<<<2, 256, 0, stream>>>(qkv_b, qkv_bs);
    k_pack_projw<<<64, 256, 0, stream>>>(proj_w, proj_wp);
    k_pack_mlp<<<512, 256, 0, stream>>>(fc1_w, fc2_w, wpack);

    k_block1<<<4096, 256, 0, stream>>>(x, ln1_s, ln1_b, qkv_wp, qkv_bs, rel_bias,
                                       proj_wp, proj_b, out);
    k_block2<<<2048, 512, 0, stream>>>(out, ln2_s, ln2_b, wpack, fc1_b, fc2_b);
}

// Round 10
// 223.542 us; speedup vs baseline: 3.2167x; 1.0428x over previous
//
#include <hip/hip_runtime.h>

typedef __bf16 bf16x8 __attribute__((ext_vector_type(8)));
typedef __bf16 bf16x4 __attribute__((ext_vector_type(4)));
typedef float f32x4 __attribute__((ext_vector_type(4)));
typedef unsigned short us8 __attribute__((ext_vector_type(8)));
typedef unsigned short us4 __attribute__((ext_vector_type(4)));
typedef short sh4 __attribute__((ext_vector_type(4)));

#define SCALE_Q 0.17677669529663687f  // 32^-0.5

__device__ __forceinline__ unsigned short f2b(float f) {
    __bf16 h = (__bf16)f;
    return __builtin_bit_cast(unsigned short, h);
}
__device__ __forceinline__ float b2f(unsigned short h) {
    union { unsigned u; float f; } v; v.u = ((unsigned)h) << 16;
    return v.f;
}
__device__ __forceinline__ f32x4 mfma16(us8 a, us8 b, f32x4 c) {
    return __builtin_amdgcn_mfma_f32_16x16x32_bf16(
        __builtin_bit_cast(bf16x8, a), __builtin_bit_cast(bf16x8, b), c, 0, 0, 0);
}

#if __has_builtin(__builtin_amdgcn_mfma_f32_16x16x16bf16_1k)
__device__ __forceinline__ f32x4 mfma16k16(us4 a, us4 b, f32x4 c) {
    return __builtin_amdgcn_mfma_f32_16x16x16bf16_1k(
        __builtin_bit_cast(sh4, a), __builtin_bit_cast(sh4, b), c, 0, 0, 0);
}
#elif __has_builtin(__builtin_amdgcn_mfma_f32_16x16x16_bf16)
__device__ __forceinline__ f32x4 mfma16k16(us4 a, us4 b, f32x4 c) {
    return __builtin_amdgcn_mfma_f32_16x16x16_bf16(
        __builtin_bit_cast(bf16x4, a), __builtin_bit_cast(bf16x4, b), c, 0, 0, 0);
}
#else
__device__ __forceinline__ f32x4 mfma16k16(us4 a, us4 b, f32x4 c) {
    asm volatile("v_mfma_f32_16x16x16_bf16 %0, %1, %2, %0"
                 : "+v"(c) : "v"(a), "v"(b));
    return c;
}
#endif

__device__ __forceinline__ us8 lds_ld8(const unsigned short* base, int byteoff) {
    return *(const us8*)((const char*)base + byteoff);
}
__device__ __forceinline__ void lds_st8(unsigned short* base, int byteoff, us8 v) {
    *(us8*)((char*)base + byteoff) = v;
}

// ---------- pack qkv weights into per-(wave,ct) fragment blocks, fold SCALE_Q ----------
__global__ void k_pack_qkvw(const float* __restrict__ qkv_w, unsigned short* __restrict__ dst) {
    int gid = blockIdx.x * 256 + threadIdx.x;          // 49152
    int blk = gid >> 9, rem = gid & 511;
    int lane = rem >> 3, j = rem & 7;
    int w = blk / 24, r1 = blk % 24, ct = r1 >> 2, kk = r1 & 3;
    int col = w * 96 + ct * 16 + (lane & 15);
    int k = kk * 32 + (lane >> 4) * 8 + j;
    float v = qkv_w[k * 384 + col];
    if (col < 128) v *= SCALE_Q;
    dst[gid] = f2b(v);
}
__global__ void k_scale_qkvb(const float* __restrict__ qkv_b, float* __restrict__ dst) {
    int i = blockIdx.x * 256 + threadIdx.x;
    if (i < 384) dst[i] = qkv_b[i] * (i < 128 ? SCALE_Q : 1.f);
}
__global__ void k_pack_projw(const float* __restrict__ proj_w, unsigned short* __restrict__ dst) {
    int gid = blockIdx.x * 256 + threadIdx.x;          // 16384
    int blk = gid >> 9, rem = gid & 511;
    int lane = rem >> 3, j = rem & 7;
    int w = blk >> 3, r1 = blk & 7, ct = r1 >> 2, kk = r1 & 3;
    int col = w * 32 + ct * 16 + (lane & 15);
    int k = kk * 32 + (lane >> 4) * 8 + j;
    dst[gid] = f2b(proj_w[k * 128 + col]);
}

// ---------- pack MLP weights: per ct-PAIR 16KB slices ----------
// slice P (8192 shorts):
//  [0,2048):    fc1 half-A: kk*512+lane*8+j = fc1_w[kk*32+(lane>>4)*8+j][P*32+(m>>2)*8+0+(m&3)], m=lane&15
//  [2048,4096): fc1 half-B: same with +4
//  [4096,8192): fc2 K=32 frag: co*512+lane*8+j = fc2_w[P*32+(lane>>4)*8+j][co*16+m]
__global__ void k_pack_mlp(const float* __restrict__ fc1_w, const float* __restrict__ fc2_w,
                           unsigned short* __restrict__ wPack) {
    int gid = blockIdx.x * 256 + threadIdx.x;          // 131072
    int pair = gid >> 13;
    int rem = gid & 8191;
    float v;
    if (rem < 4096) {
        int half = rem >> 11;
        int r2 = rem & 2047;
        int kk = r2 >> 9, r3 = r2 & 511;
        int lane = r3 >> 3, j = r3 & 7;
        int m = lane & 15;
        int col = pair * 32 + (m >> 2) * 8 + half * 4 + (m & 3);
        int k = kk * 32 + (lane >> 4) * 8 + j;
        v = fc1_w[(size_t)k * 512 + col];
    } else {
        int r2 = rem - 4096;
        int co = r2 >> 9, r3 = r2 & 511;
        int lane = r3 >> 3, j = r3 & 7;
        int k = pair * 32 + (lane >> 4) * 8 + j;
        v = fc2_w[(size_t)k * 128 + co * 16 + (lane & 15)];
    }
    wPack[gid] = f2b(v);
}

// =====================================================================
// K1 v2 (unchanged from r9): LN1 + roll + partition + QKV + attn + proj
// =====================================================================
__global__ __launch_bounds__(256, 3) void k_block1(
    const float* __restrict__ x,
    const float* __restrict__ ln1s, const float* __restrict__ ln1b,
    const unsigned short* __restrict__ qkvWp, const float* __restrict__ qkvBs,
    const float* __restrict__ relb,
    const unsigned short* __restrict__ projWp, const float* __restrict__ projB,
    float* __restrict__ out)
{
    __shared__ unsigned short sm[4 * 6144];   // 48 KB
    __shared__ float sbias[196];
    const int tid = threadIdx.x;
    const int wave = tid >> 6, lane = tid & 63;
    const int g = lane >> 4, m16 = lane & 15;
    if (tid < 196) sbias[tid] = relb[tid];
    const int win0 = blockIdx.x * 4;
    const int winM = win0 + wave;
    const int bbM = winM >> 8, whM = (winM >> 4) & 15, wnM = winM & 15;

    {
        float4 sc0 = *(const float4*)(ln1s + m16 * 8);
        float4 sc1 = *(const float4*)(ln1s + m16 * 8 + 4);
        float4 bi0 = *(const float4*)(ln1b + m16 * 8);
        float4 bi1 = *(const float4*)(ln1b + m16 * 8 + 4);
        #pragma unroll
        for (int it = 0; it < 4; ++it) {
            int tok = it * 4 + g;
            int ti = tok >> 2, tj = tok & 3;
            int hh = (whM * 4 + ti + 2) & 63, ww = (wnM * 4 + tj + 2) & 63;
            const float* xr = x + ((((size_t)bbM << 12) | (hh << 6) | ww) * 128) + m16 * 8;
            float4 v0 = *(const float4*)xr, v1 = *(const float4*)(xr + 4);
            float sum = v0.x + v0.y + v0.z + v0.w + v1.x + v1.y + v1.z + v1.w;
            float sq  = v0.x*v0.x + v0.y*v0.y + v0.z*v0.z + v0.w*v0.w
                      + v1.x*v1.x + v1.y*v1.y + v1.z*v1.z + v1.w*v1.w;
            #pragma unroll
            for (int m = 1; m < 16; m <<= 1) { sum += __shfl_xor(sum, m); sq += __shfl_xor(sq, m); }
            float mu = sum * 0.0078125f;
            float rstd = rsqrtf(sq * 0.0078125f - mu * mu + 1e-6f);
            us8 o;
            o[0] = f2b((v0.x - mu) * rstd * sc0.x + bi0.x);
            o[1] = f2b((v0.y - mu) * rstd * sc0.y + bi0.y);
            o[2] = f2b((v0.z - mu) * rstd * sc0.z + bi0.z);
            o[3] = f2b((v0.w - mu) * rstd * sc0.w + bi0.w);
            o[4] = f2b((v1.x - mu) * rstd * sc1.x + bi1.x);
            o[5] = f2b((v1.y - mu) * rstd * sc1.y + bi1.y);
            o[6] = f2b((v1.z - mu) * rstd * sc1.z + bi1.z);
            o[7] = f2b((v1.w - mu) * rstd * sc1.w + bi1.w);
            lds_st8(sm, wave * 12288 + tok * 256 + ((m16 * 16) ^ ((tok & 7) << 4)), o);
        }
    }
    __syncthreads();

    us8 afr[4][4];
    #pragma unroll
    for (int w = 0; w < 4; ++w)
        #pragma unroll
        for (int k = 0; k < 4; ++k)
            afr[w][k] = lds_ld8(sm, w * 12288 + m16 * 256 + ((k * 64 + g * 16) ^ ((m16 & 7) << 4)));
    __syncthreads();

    #pragma unroll
    for (int ct = 0; ct < 6; ++ct) {
        const unsigned short* bp = qkvWp + (size_t)((wave * 6 + ct) * 4) * 512 + lane * 8;
        us8 b0 = *(const us8*)(bp);
        us8 b1 = *(const us8*)(bp + 512);
        us8 b2 = *(const us8*)(bp + 1024);
        us8 b3 = *(const us8*)(bp + 1536);
        f32x4 acc[4] = {{0.f,0.f,0.f,0.f},{0.f,0.f,0.f,0.f},{0.f,0.f,0.f,0.f},{0.f,0.f,0.f,0.f}};
        #pragma unroll
        for (int w = 0; w < 4; ++w) {
            acc[w] = mfma16(afr[w][0], b0, acc[w]);
            acc[w] = mfma16(afr[w][1], b1, acc[w]);
            acc[w] = mfma16(afr[w][2], b2, acc[w]);
            acc[w] = mfma16(afr[w][3], b3, acc[w]);
        }
        const int c = wave * 96 + ct * 16 + m16;
        const float bias = qkvBs[c];
        const int s = c >> 7;
        const int rem = c & 127, hq = rem >> 5, hd = rem & 31;
        #pragma unroll
        for (int w = 0; w < 4; ++w) {
            const int base = w * 12288;
            if (s == 2) {
                us4 pk;
                #pragma unroll
                for (int jj = 0; jj < 4; ++jj) pk[jj] = f2b(acc[w][jj] + bias);
                *(us4*)((char*)sm + base + 8192 + hq * 1024 + hd * 32
                        + ((g ^ ((hd >> 2) & 3)) << 3)) = pk;
            } else {
                #pragma unroll
                for (int jj = 0; jj < 4; ++jj) {
                    int tok = g * 4 + jj;
                    int chunk = (hd >> 3) ^ ((tok >> 1) & 3);
                    *(unsigned short*)((char*)sm + base + s * 4096 + hq * 1024
                                       + tok * 64 + chunk * 16 + (hd & 7) * 2)
                        = f2b(acc[w][jj] + bias);
                }
            }
        }
    }
    __syncthreads();

    {
        const int base = wave * 12288;
        const int ti = m16 >> 2, tj = m16 & 3;
        const int hhq = whM * 4 + ti, wwq = wnM * 4 + tj;
        const int myid = (hhq < 60 ? 0 : (hhq < 62 ? 3 : 6)) + (wwq < 60 ? 0 : (wwq < 62 ? 1 : 2));
        const int qkswz = (g ^ ((m16 >> 1) & 3)) * 16;
        const int vswz  = (g ^ ((m16 >> 2) & 3)) << 3;
        f32x4 po[4][2];
        #pragma unroll
        for (int h = 0; h < 4; ++h) {
            us8 kf = lds_ld8(sm, base + 4096 + h * 1024 + m16 * 64 + qkswz);
            us8 qf = lds_ld8(sm, base +        h * 1024 + m16 * 64 + qkswz);
            f32x4 st = mfma16(kf, qf, (f32x4){0.f,0.f,0.f,0.f});
            float p[4];
            #pragma unroll
            for (int jj = 0; jj < 4; ++jj) {
                int kk = g * 4 + jj;
                int pi = kk >> 2, pj = kk & 3;
                int hhk = whM * 4 + pi, wwk = wnM * 4 + pj;
                int pid = (hhk < 60 ? 0 : (hhk < 62 ? 3 : 6)) + (wwk < 60 ? 0 : (wwk < 62 ? 1 : 2));
                float v = st[jj] + sbias[((ti - pi + 3) * 7 + (tj - pj + 3)) * 4 + h];
                p[jj] = (pid != myid) ? v - 100.f : v;
            }
            #pragma unroll
            for (int rep = 0; rep < 2; ++rep) {
                float mx = fmaxf(fmaxf(p[0], p[1]), fmaxf(p[2], p[3]));
                mx = fmaxf(mx, __shfl_xor(mx, 16));
                mx = fmaxf(mx, __shfl_xor(mx, 32));
                float ssum = 0.f;
                #pragma unroll
                for (int jj = 0; jj < 4; ++jj) { p[jj] = __expf(p[jj] - mx); ssum += p[jj]; }
                ssum += __shfl_xor(ssum, 16);
                ssum += __shfl_xor(ssum, 32);
                float inv = 1.f / ssum;
                #pragma unroll
                for (int jj = 0; jj < 4; ++jj) p[jj] *= inv;
            }
            us4 pf;
            #pragma unroll
            for (int jj = 0; jj < 4; ++jj) pf[jj] = f2b(p[jj]);
            #pragma unroll
            for (int dh = 0; dh < 2; ++dh) {
                us4 vf = *(const us4*)((const char*)sm + base + 8192 + h * 1024
                                       + (dh * 16 + m16) * 32 + vswz);
                po[h][dh] = mfma16k16(vf, pf, (f32x4){0.f,0.f,0.f,0.f});
            }
        }
        #pragma unroll
        for (int h = 0; h < 4; ++h)
            #pragma unroll
            for (int dh = 0; dh < 2; ++dh) {
                us4 pk;
                #pragma unroll
                for (int jj = 0; jj < 4; ++jj) pk[jj] = f2b(po[h][dh][jj]);
                *(us4*)((char*)sm + base + m16 * 256
                        + ((h * 64 + dh * 32 + g * 8) ^ ((m16 & 7) << 4))) = pk;
            }
    }
    __syncthreads();

    {
        us8 cfr[4][4];
        #pragma unroll
        for (int w = 0; w < 4; ++w)
            #pragma unroll
            for (int k = 0; k < 4; ++k)
                cfr[w][k] = lds_ld8(sm, w * 12288 + m16 * 256 + ((k * 64 + g * 16) ^ ((m16 & 7) << 4)));
        #pragma unroll
        for (int ct = 0; ct < 2; ++ct) {
            const unsigned short* bp = projWp + (size_t)((wave * 2 + ct) * 4) * 512 + lane * 8;
            us8 b0 = *(const us8*)(bp);
            us8 b1 = *(const us8*)(bp + 512);
            us8 b2 = *(const us8*)(bp + 1024);
            us8 b3 = *(const us8*)(bp + 1536);
            const int c = wave * 32 + ct * 16 + m16;
            const float pb = projB[c];
            #pragma unroll
            for (int w = 0; w < 4; ++w) {
                f32x4 acc = {0.f, 0.f, 0.f, 0.f};
                acc = mfma16(cfr[w][0], b0, acc);
                acc = mfma16(cfr[w][1], b1, acc);
                acc = mfma16(cfr[w][2], b2, acc);
                acc = mfma16(cfr[w][3], b3, acc);
                const int winw = win0 + w;
                const int bb = winw >> 8, wh = (winw >> 4) & 15, wn = winw & 15;
                #pragma unroll
                for (int jj = 0; jj < 4; ++jj) {
                    int tok = g * 4 + jj;
                    int hh3 = (wh * 4 + (tok >> 2) + 2) & 63;
                    int ww3 = (wn * 4 + (tok & 3) + 2) & 63;
                    size_t t = (((size_t)bb << 12) | (hh3 << 6) | ww3);
                    out[t * 128 + c] = acc[jj] + pb + x[t * 128 + c];
                }
            }
        }
    }
}

// =====================================================================
// K2 v7: LN2 + FC1 + GELU + FC2 + residual. ct-PAIR iterations:
// permuted FC1 packing makes GELU output the K=32 A-frag for FC2
// (full-rate MFMA). 16 iters, 17 barriers. LDS 32KB (scratch aliases
// the weight double-buffer; extra prologue barrier protects overlap).
// =====================================================================
__global__ __launch_bounds__(512, 4) void k_block2(
    float* __restrict__ out,
    const float* __restrict__ ln2s, const float* __restrict__ ln2b,
    const unsigned short* __restrict__ wPack,
    const float* __restrict__ fc1B, const float* __restrict__ fc2B)
{
    __shared__ unsigned short smem[16384];   // 32KB: scratch (8x4KB) then wbuf[2][16KB]
    const int tid = threadIdx.x;
    const int wave = tid >> 6, lane = tid & 63;
    const int g = lane >> 4, m16 = lane & 15;
    const size_t r0 = (size_t)blockIdx.x * 128;
    unsigned short* scr = &smem[wave * 2048];

    // ---- LN2 on this wave's 16 rows -> wave-private scratch ----
    {
        float4 sc0 = *(const float4*)(ln2s + m16 * 8);
        float4 sc1 = *(const float4*)(ln2s + m16 * 8 + 4);
        float4 bi0 = *(const float4*)(ln2b + m16 * 8);
        float4 bi1 = *(const float4*)(ln2b + m16 * 8 + 4);
        #pragma unroll
        for (int it = 0; it < 4; ++it) {
            int lr = it * 4 + g;
            const float* xr = out + (r0 + wave * 16 + lr) * 128 + m16 * 8;
            float4 v0 = *(const float4*)xr, v1 = *(const float4*)(xr + 4);
            float sum = v0.x + v0.y + v0.z + v0.w + v1.x + v1.y + v1.z + v1.w;
            float sq  = v0.x*v0.x + v0.y*v0.y + v0.z*v0.z + v0.w*v0.w
                      + v1.x*v1.x + v1.y*v1.y + v1.z*v1.z + v1.w*v1.w;
            #pragma unroll
            for (int m = 1; m < 16; m <<= 1) { sum += __shfl_xor(sum, m); sq += __shfl_xor(sq, m); }
            float mu = sum * 0.0078125f;
            float rstd = rsqrtf(sq * 0.0078125f - mu * mu + 1e-6f);
            us8 o;
            o[0] = f2b((v0.x - mu) * rstd * sc0.x + bi0.x);
            o[1] = f2b((v0.y - mu) * rstd * sc0.y + bi0.y);
            o[2] = f2b((v0.z - mu) * rstd * sc0.z + bi0.z);
            o[3] = f2b((v0.w - mu) * rstd * sc0.w + bi0.w);
            o[4] = f2b((v1.x - mu) * rstd * sc1.x + bi1.x);
            o[5] = f2b((v1.y - mu) * rstd * sc1.y + bi1.y);
            o[6] = f2b((v1.z - mu) * rstd * sc1.z + bi1.z);
            o[7] = f2b((v1.w - mu) * rstd * sc1.w + bi1.w);
            lds_st8(scr, lr * 256 + ((m16 * 16) ^ ((lr & 7) << 4)), o);
        }
    }
    // hoist x B-frags (wave-local lgkm ordering)
    us8 bx[4];
    #pragma unroll
    for (int kk = 0; kk < 4; ++kk)
        bx[kk] = lds_ld8(scr, m16 * 256 + ((kk * 64 + g * 16) ^ ((m16 & 7) << 4)));
    __syncthreads();          // scratch dead everywhere; safe to overwrite with weights

    // ---- stage pair 0 into buf0 (2 x 16B gload_lds per thread) ----
    #pragma unroll
    for (int sub = 0; sub < 2; ++sub) {
        const unsigned short* src = wPack + sub * 4096 + tid * 8;
        unsigned short* dst = &smem[sub * 4096 + wave * 512];
#if __has_builtin(__builtin_amdgcn_global_load_lds)
        __builtin_amdgcn_global_load_lds(
            (const __attribute__((address_space(1))) void*)src,
            (__attribute__((address_space(3))) void*)dst, 16, 0, 0);
#else
        *(us8*)(dst + lane * 8) = *(const us8*)src;
#endif
    }
    __syncthreads();          // pair 0 staged

    f32x4 accO[8];
    #pragma unroll
    for (int co = 0; co < 8; ++co) accO[co] = (f32x4){0.f, 0.f, 0.f, 0.f};

    for (int p = 0; p < 16; ++p) {
        if (p < 15) {
            #pragma unroll
            for (int sub = 0; sub < 2; ++sub) {
                const unsigned short* src = wPack + (p + 1) * 8192 + sub * 4096 + tid * 8;
                unsigned short* dst = &smem[((p + 1) & 1) * 8192 + sub * 4096 + wave * 512];
#if __has_builtin(__builtin_amdgcn_global_load_lds)
                __builtin_amdgcn_global_load_lds(
                    (const __attribute__((address_space(1))) void*)src,
                    (__attribute__((address_space(3))) void*)dst, 16, 0, 0);
#else
                *(us8*)(dst + lane * 8) = *(const us8*)src;
#endif
            }
        }
        const char* wb = (const char*)&smem[(p & 1) * 8192];
        // FC1^T half A: hA[jj] = hid[row=wave*16+m16][col = p*32 + g*8 + jj]
        f32x4 hA = {0.f, 0.f, 0.f, 0.f};
        hA = mfma16(*(const us8*)(wb +    0 + lane * 16), bx[0], hA);
        hA = mfma16(*(const us8*)(wb + 1024 + lane * 16), bx[1], hA);
        hA = mfma16(*(const us8*)(wb + 2048 + lane * 16), bx[2], hA);
        hA = mfma16(*(const us8*)(wb + 3072 + lane * 16), bx[3], hA);
        // FC1^T half B: hB[jj] = col p*32 + g*8 + 4 + jj
        f32x4 hB = {0.f, 0.f, 0.f, 0.f};
        hB = mfma16(*(const us8*)(wb + 4096 + lane * 16), bx[0], hB);
        hB = mfma16(*(const us8*)(wb + 5120 + lane * 16), bx[1], hB);
        hB = mfma16(*(const us8*)(wb + 6144 + lane * 16), bx[2], hB);
        hB = mfma16(*(const us8*)(wb + 7168 + lane * 16), bx[3], hB);
        float4 bA = *(const float4*)(fc1B + p * 32 + g * 8);
        float4 bB = *(const float4*)(fc1B + p * 32 + g * 8 + 4);
        us8 pa;
        #pragma unroll
        for (int jj = 0; jj < 4; ++jj) {
            float v = hA[jj] + ((const float*)&bA)[jj];
            float z = v + 0.044715f * v * v * v;
            float e = __builtin_amdgcn_exp2f(-2.3022082f * z);   // exp(-1.59577 z)
            pa[jj] = f2b(v * __builtin_amdgcn_rcpf(1.f + e));
            float w = hB[jj] + ((const float*)&bB)[jj];
            float z2 = w + 0.044715f * w * w * w;
            float e2 = __builtin_amdgcn_exp2f(-2.3022082f * z2);
            pa[4 + jj] = f2b(w * __builtin_amdgcn_rcpf(1.f + e2));
        }
        // FC2: 8 full-rate K=32 MFMAs
        #pragma unroll
        for (int co = 0; co < 8; ++co) {
            us8 bw = *(const us8*)(wb + 8192 + co * 1024 + lane * 16);
            accO[co] = mfma16(pa, bw, accO[co]);
        }
        __syncthreads();
    }

    // ---- epilogue: bias + residual, in-place fp32 ----
    #pragma unroll
    for (int co = 0; co < 8; ++co) {
        int col = co * 16 + m16;
        float b2v = fc2B[col];
        #pragma unroll
        for (int jj = 0; jj < 4; ++jj) {
            size_t row = r0 + wave * 16 + g * 4 + jj;
            float* op = out + row * 128 + col;
            *op = accO[co][jj] + b2v + *op;
        }
    }
}

// ---------- launch ----------
extern "C" void kernel_launch(void* const* d_in, const int* in_sizes, int n_in,
                              void* d_out, int out_size, void* d_ws, size_t ws_size,
                              hipStream_t stream) {
    const float* x        = (const float*)d_in[0];
    const float* ln1_s    = (const float*)d_in[1];
    const float* ln1_b    = (const float*)d_in[2];
    const float* qkv_w    = (const float*)d_in[3];
    const float* qkv_b    = (const float*)d_in[4];
    const float* rel_bias = (const float*)d_in[5];
    const float* proj_w   = (const float*)d_in[6];
    const float* proj_b   = (const float*)d_in[7];
    const float* ln2_s    = (const float*)d_in[8];
    const float* ln2_b    = (const float*)d_in[9];
    const float* fc1_w    = (const float*)d_in[10];
    const float* fc1_b    = (const float*)d_in[11];
    const float* fc2_w    = (const float*)d_in[12];
    const float* fc2_b    = (const float*)d_in[13];
    float* out = (float*)d_out;
    char* ws = (char*)d_ws;

    unsigned short* qkv_wp  = (unsigned short*)(ws);             // 96KB packed qkv frags
    unsigned short* proj_wp = (unsigned short*)(ws + 98304);     // 32KB packed proj frags
    unsigned short* wpack   = (unsigned short*)(ws + 131072);    // 256KB packed MLP (16x16KB)
    float*          qkv_bs  = (float*)(ws + 393216);             // 1.5KB scaled qkv bias

    k_pack_qkvw<<<192, 256, 0, stream>>>(qkv_w, qkv_wp);
    k_scale_qkvb<<<2, 256, 0, stream>>>(qkv_b, qkv_bs);
    k_pack_projw<<<64, 256, 0, stream>>>(proj_w, proj_wp);
    k_pack_mlp<<<512, 256, 0, stream>>>(fc1_w, fc2_w, wpack);

    k_block1<<<4096, 256, 0, stream>>>(x, ln1_s, ln1_b, qkv_wp, qkv_bs, rel_bias,
                                       proj_wp, proj_b, out);
    k_block2<<<2048, 512, 0, stream>>>(out, ln2_s, ln2_b, wpack, fc1_b, fc2_b);
}

// Round 11
// 216.481 us; speedup vs baseline: 3.3216x; 1.0326x over previous
//
#include <hip/hip_runtime.h>

typedef __bf16 bf16x8 __attribute__((ext_vector_type(8)));
typedef __bf16 bf16x4 __attribute__((ext_vector_type(4)));
typedef float f32x4 __attribute__((ext_vector_type(4)));
typedef unsigned short us8 __attribute__((ext_vector_type(8)));
typedef unsigned short us4 __attribute__((ext_vector_type(4)));
typedef short sh4 __attribute__((ext_vector_type(4)));

#define SCALE_Q 0.17677669529663687f  // 32^-0.5

__device__ __forceinline__ unsigned short f2b(float f) {
    __bf16 h = (__bf16)f;
    return __builtin_bit_cast(unsigned short, h);
}
__device__ __forceinline__ float b2f(unsigned short h) {
    union { unsigned u; float f; } v; v.u = ((unsigned)h) << 16;
    return v.f;
}
__device__ __forceinline__ f32x4 mfma16(us8 a, us8 b, f32x4 c) {
    return __builtin_amdgcn_mfma_f32_16x16x32_bf16(
        __builtin_bit_cast(bf16x8, a), __builtin_bit_cast(bf16x8, b), c, 0, 0, 0);
}

#if __has_builtin(__builtin_amdgcn_mfma_f32_16x16x16bf16_1k)
__device__ __forceinline__ f32x4 mfma16k16(us4 a, us4 b, f32x4 c) {
    return __builtin_amdgcn_mfma_f32_16x16x16bf16_1k(
        __builtin_bit_cast(sh4, a), __builtin_bit_cast(sh4, b), c, 0, 0, 0);
}
#elif __has_builtin(__builtin_amdgcn_mfma_f32_16x16x16_bf16)
__device__ __forceinline__ f32x4 mfma16k16(us4 a, us4 b, f32x4 c) {
    return __builtin_amdgcn_mfma_f32_16x16x16_bf16(
        __builtin_bit_cast(bf16x4, a), __builtin_bit_cast(bf16x4, b), c, 0, 0, 0);
}
#else
__device__ __forceinline__ f32x4 mfma16k16(us4 a, us4 b, f32x4 c) {
    asm volatile("v_mfma_f32_16x16x16_bf16 %0, %1, %2, %0"
                 : "+v"(c) : "v"(a), "v"(b));
    return c;
}
#endif

__device__ __forceinline__ us8 lds_ld8(const unsigned short* base, int byteoff) {
    return *(const us8*)((const char*)base + byteoff);
}
__device__ __forceinline__ void lds_st8(unsigned short* base, int byteoff, us8 v) {
    *(us8*)((char*)base + byteoff) = v;
}

// ---------- pack qkv weights into per-(wave,ct) fragment blocks, fold SCALE_Q ----------
__global__ void k_pack_qkvw(const float* __restrict__ qkv_w, unsigned short* __restrict__ dst) {
    int gid = blockIdx.x * 256 + threadIdx.x;          // 49152
    int blk = gid >> 9, rem = gid & 511;
    int lane = rem >> 3, j = rem & 7;
    int w = blk / 24, r1 = blk % 24, ct = r1 >> 2, kk = r1 & 3;
    int col = w * 96 + ct * 16 + (lane & 15);
    int k = kk * 32 + (lane >> 4) * 8 + j;
    float v = qkv_w[k * 384 + col];
    if (col < 128) v *= SCALE_Q;
    dst[gid] = f2b(v);
}
__global__ void k_scale_qkvb(const float* __restrict__ qkv_b, float* __restrict__ dst) {
    int i = blockIdx.x * 256 + threadIdx.x;
    if (i < 384) dst[i] = qkv_b[i] * (i < 128 ? SCALE_Q : 1.f);
}
__global__ void k_pack_projw(const float* __restrict__ proj_w, unsigned short* __restrict__ dst) {
    int gid = blockIdx.x * 256 + threadIdx.x;          // 16384
    int blk = gid >> 9, rem = gid & 511;
    int lane = rem >> 3, j = rem & 7;
    int w = blk >> 3, r1 = blk & 7, ct = r1 >> 2, kk = r1 & 3;
    int col = w * 32 + ct * 16 + (lane & 15);
    int k = kk * 32 + (lane >> 4) * 8 + j;
    dst[gid] = f2b(proj_w[k * 128 + col]);
}

// ---------- pack MLP weights: per ct-PAIR 16KB slices (unchanged layout) ----------
__global__ void k_pack_mlp(const float* __restrict__ fc1_w, const float* __restrict__ fc2_w,
                           unsigned short* __restrict__ wPack) {
    int gid = blockIdx.x * 256 + threadIdx.x;          // 131072
    int pair = gid >> 13;
    int rem = gid & 8191;
    float v;
    if (rem < 4096) {
        int half = rem >> 11;
        int r2 = rem & 2047;
        int kk = r2 >> 9, r3 = r2 & 511;
        int lane = r3 >> 3, j = r3 & 7;
        int m = lane & 15;
        int col = pair * 32 + (m >> 2) * 8 + half * 4 + (m & 3);
        int k = kk * 32 + (lane >> 4) * 8 + j;
        v = fc1_w[(size_t)k * 512 + col];
    } else {
        int r2 = rem - 4096;
        int co = r2 >> 9, r3 = r2 & 511;
        int lane = r3 >> 3, j = r3 & 7;
        int k = pair * 32 + (lane >> 4) * 8 + j;
        v = fc2_w[(size_t)k * 128 + co * 16 + (lane & 15)];
    }
    wPack[gid] = f2b(v);
}

// =====================================================================
// K1 v2 (unchanged from r9/r10): LN1 + roll + partition + QKV + attn + proj
// =====================================================================
__global__ __launch_bounds__(256, 3) void k_block1(
    const float* __restrict__ x,
    const float* __restrict__ ln1s, const float* __restrict__ ln1b,
    const unsigned short* __restrict__ qkvWp, const float* __restrict__ qkvBs,
    const float* __restrict__ relb,
    const unsigned short* __restrict__ projWp, const float* __restrict__ projB,
    float* __restrict__ out)
{
    __shared__ unsigned short sm[4 * 6144];   // 48 KB
    __shared__ float sbias[196];
    const int tid = threadIdx.x;
    const int wave = tid >> 6, lane = tid & 63;
    const int g = lane >> 4, m16 = lane & 15;
    if (tid < 196) sbias[tid] = relb[tid];
    const int win0 = blockIdx.x * 4;
    const int winM = win0 + wave;
    const int bbM = winM >> 8, whM = (winM >> 4) & 15, wnM = winM & 15;

    {
        float4 sc0 = *(const float4*)(ln1s + m16 * 8);
        float4 sc1 = *(const float4*)(ln1s + m16 * 8 + 4);
        float4 bi0 = *(const float4*)(ln1b + m16 * 8);
        float4 bi1 = *(const float4*)(ln1b + m16 * 8 + 4);
        #pragma unroll
        for (int it = 0; it < 4; ++it) {
            int tok = it * 4 + g;
            int ti = tok >> 2, tj = tok & 3;
            int hh = (whM * 4 + ti + 2) & 63, ww = (wnM * 4 + tj + 2) & 63;
            const float* xr = x + ((((size_t)bbM << 12) | (hh << 6) | ww) * 128) + m16 * 8;
            float4 v0 = *(const float4*)xr, v1 = *(const float4*)(xr + 4);
            float sum = v0.x + v0.y + v0.z + v0.w + v1.x + v1.y + v1.z + v1.w;
            float sq  = v0.x*v0.x + v0.y*v0.y + v0.z*v0.z + v0.w*v0.w
                      + v1.x*v1.x + v1.y*v1.y + v1.z*v1.z + v1.w*v1.w;
            #pragma unroll
            for (int m = 1; m < 16; m <<= 1) { sum += __shfl_xor(sum, m); sq += __shfl_xor(sq, m); }
            float mu = sum * 0.0078125f;
            float rstd = rsqrtf(sq * 0.0078125f - mu * mu + 1e-6f);
            us8 o;
            o[0] = f2b((v0.x - mu) * rstd * sc0.x + bi0.x);
            o[1] = f2b((v0.y - mu) * rstd * sc0.y + bi0.y);
            o[2] = f2b((v0.z - mu) * rstd * sc0.z + bi0.z);
            o[3] = f2b((v0.w - mu) * rstd * sc0.w + bi0.w);
            o[4] = f2b((v1.x - mu) * rstd * sc1.x + bi1.x);
            o[5] = f2b((v1.y - mu) * rstd * sc1.y + bi1.y);
            o[6] = f2b((v1.z - mu) * rstd * sc1.z + bi1.z);
            o[7] = f2b((v1.w - mu) * rstd * sc1.w + bi1.w);
            lds_st8(sm, wave * 12288 + tok * 256 + ((m16 * 16) ^ ((tok & 7) << 4)), o);
        }
    }
    __syncthreads();

    us8 afr[4][4];
    #pragma unroll
    for (int w = 0; w < 4; ++w)
        #pragma unroll
        for (int k = 0; k < 4; ++k)
            afr[w][k] = lds_ld8(sm, w * 12288 + m16 * 256 + ((k * 64 + g * 16) ^ ((m16 & 7) << 4)));
    __syncthreads();

    #pragma unroll
    for (int ct = 0; ct < 6; ++ct) {
        const unsigned short* bp = qkvWp + (size_t)((wave * 6 + ct) * 4) * 512 + lane * 8;
        us8 b0 = *(const us8*)(bp);
        us8 b1 = *(const us8*)(bp + 512);
        us8 b2 = *(const us8*)(bp + 1024);
        us8 b3 = *(const us8*)(bp + 1536);
        f32x4 acc[4] = {{0.f,0.f,0.f,0.f},{0.f,0.f,0.f,0.f},{0.f,0.f,0.f,0.f},{0.f,0.f,0.f,0.f}};
        #pragma unroll
        for (int w = 0; w < 4; ++w) {
            acc[w] = mfma16(afr[w][0], b0, acc[w]);
            acc[w] = mfma16(afr[w][1], b1, acc[w]);
            acc[w] = mfma16(afr[w][2], b2, acc[w]);
            acc[w] = mfma16(afr[w][3], b3, acc[w]);
        }
        const int c = wave * 96 + ct * 16 + m16;
        const float bias = qkvBs[c];
        const int s = c >> 7;
        const int rem = c & 127, hq = rem >> 5, hd = rem & 31;
        #pragma unroll
        for (int w = 0; w < 4; ++w) {
            const int base = w * 12288;
            if (s == 2) {
                us4 pk;
                #pragma unroll
                for (int jj = 0; jj < 4; ++jj) pk[jj] = f2b(acc[w][jj] + bias);
                *(us4*)((char*)sm + base + 8192 + hq * 1024 + hd * 32
                        + ((g ^ ((hd >> 2) & 3)) << 3)) = pk;
            } else {
                #pragma unroll
                for (int jj = 0; jj < 4; ++jj) {
                    int tok = g * 4 + jj;
                    int chunk = (hd >> 3) ^ ((tok >> 1) & 3);
                    *(unsigned short*)((char*)sm + base + s * 4096 + hq * 1024
                                       + tok * 64 + chunk * 16 + (hd & 7) * 2)
                        = f2b(acc[w][jj] + bias);
                }
            }
        }
    }
    __syncthreads();

    {
        const int base = wave * 12288;
        const int ti = m16 >> 2, tj = m16 & 3;
        const int hhq = whM * 4 + ti, wwq = wnM * 4 + tj;
        const int myid = (hhq < 60 ? 0 : (hhq < 62 ? 3 : 6)) + (wwq < 60 ? 0 : (wwq < 62 ? 1 : 2));
        const int qkswz = (g ^ ((m16 >> 1) & 3)) * 16;
        const int vswz  = (g ^ ((m16 >> 2) & 3)) << 3;
        f32x4 po[4][2];
        #pragma unroll
        for (int h = 0; h < 4; ++h) {
            us8 kf = lds_ld8(sm, base + 4096 + h * 1024 + m16 * 64 + qkswz);
            us8 qf = lds_ld8(sm, base +        h * 1024 + m16 * 64 + qkswz);
            f32x4 st = mfma16(kf, qf, (f32x4){0.f,0.f,0.f,0.f});
            float p[4];
            #pragma unroll
            for (int jj = 0; jj < 4; ++jj) {
                int kk = g * 4 + jj;
                int pi = kk >> 2, pj = kk & 3;
                int hhk = whM * 4 + pi, wwk = wnM * 4 + pj;
                int pid = (hhk < 60 ? 0 : (hhk < 62 ? 3 : 6)) + (wwk < 60 ? 0 : (wwk < 62 ? 1 : 2));
                float v = st[jj] + sbias[((ti - pi + 3) * 7 + (tj - pj + 3)) * 4 + h];
                p[jj] = (pid != myid) ? v - 100.f : v;
            }
            #pragma unroll
            for (int rep = 0; rep < 2; ++rep) {
                float mx = fmaxf(fmaxf(p[0], p[1]), fmaxf(p[2], p[3]));
                mx = fmaxf(mx, __shfl_xor(mx, 16));
                mx = fmaxf(mx, __shfl_xor(mx, 32));
                float ssum = 0.f;
                #pragma unroll
                for (int jj = 0; jj < 4; ++jj) { p[jj] = __expf(p[jj] - mx); ssum += p[jj]; }
                ssum += __shfl_xor(ssum, 16);
                ssum += __shfl_xor(ssum, 32);
                float inv = 1.f / ssum;
                #pragma unroll
                for (int jj = 0; jj < 4; ++jj) p[jj] *= inv;
            }
            us4 pf;
            #pragma unroll
            for (int jj = 0; jj < 4; ++jj) pf[jj] = f2b(p[jj]);
            #pragma unroll
            for (int dh = 0; dh < 2; ++dh) {
                us4 vf = *(const us4*)((const char*)sm + base + 8192 + h * 1024
                                       + (dh * 16 + m16) * 32 + vswz);
                po[h][dh] = mfma16k16(vf, pf, (f32x4){0.f,0.f,0.f,0.f});
            }
        }
        #pragma unroll
        for (int h = 0; h < 4; ++h)
            #pragma unroll
            for (int dh = 0; dh < 2; ++dh) {
                us4 pk;
                #pragma unroll
                for (int jj = 0; jj < 4; ++jj) pk[jj] = f2b(po[h][dh][jj]);
                *(us4*)((char*)sm + base + m16 * 256
                        + ((h * 64 + dh * 32 + g * 8) ^ ((m16 & 7) << 4))) = pk;
            }
    }
    __syncthreads();

    {
        us8 cfr[4][4];
        #pragma unroll
        for (int w = 0; w < 4; ++w)
            #pragma unroll
            for (int k = 0; k < 4; ++k)
                cfr[w][k] = lds_ld8(sm, w * 12288 + m16 * 256 + ((k * 64 + g * 16) ^ ((m16 & 7) << 4)));
        #pragma unroll
        for (int ct = 0; ct < 2; ++ct) {
            const unsigned short* bp = projWp + (size_t)((wave * 2 + ct) * 4) * 512 + lane * 8;
            us8 b0 = *(const us8*)(bp);
            us8 b1 = *(const us8*)(bp + 512);
            us8 b2 = *(const us8*)(bp + 1024);
            us8 b3 = *(const us8*)(bp + 1536);
            const int c = wave * 32 + ct * 16 + m16;
            const float pb = projB[c];
            #pragma unroll
            for (int w = 0; w < 4; ++w) {
                f32x4 acc = {0.f, 0.f, 0.f, 0.f};
                acc = mfma16(cfr[w][0], b0, acc);
                acc = mfma16(cfr[w][1], b1, acc);
                acc = mfma16(cfr[w][2], b2, acc);
                acc = mfma16(cfr[w][3], b3, acc);
                const int winw = win0 + w;
                const int bb = winw >> 8, wh = (winw >> 4) & 15, wn = winw & 15;
                #pragma unroll
                for (int jj = 0; jj < 4; ++jj) {
                    int tok = g * 4 + jj;
                    int hh3 = (wh * 4 + (tok >> 2) + 2) & 63;
                    int ww3 = (wn * 4 + (tok & 3) + 2) & 63;
                    size_t t = (((size_t)bb << 12) | (hh3 << 6) | ww3);
                    out[t * 128 + c] = acc[jj] + pb + x[t * 128 + c];
                }
            }
        }
    }
}

// =====================================================================
// K2 v8: LN2 + FC1 + GELU + FC2 + residual. 4 waves x 32 rows =
// 128 rows/block (256 thr). Weight LDS reads amortized over 2 row-tiles
// per wave (halves block LDS-read traffic vs r10). launch_bounds(256,3):
// cap ~170 regs (state ~150, no spill), 3 blocks/CU, 12 waves/CU.
// LDS 48KB = 16KB LN scratch + 2x16KB weight dbuf.
// =====================================================================
__global__ __launch_bounds__(256, 3) void k_block2(
    float* __restrict__ out,
    const float* __restrict__ ln2s, const float* __restrict__ ln2b,
    const unsigned short* __restrict__ wPack,
    const float* __restrict__ fc1B, const float* __restrict__ fc2B)
{
    __shared__ unsigned short smem[24576];   // 48KB: [0,8K) scratch shorts, [8K,24K) wbuf
    const int tid = threadIdx.x;
    const int wave = tid >> 6, lane = tid & 63;
    const int g = lane >> 4, m16 = lane & 15;
    const size_t r0 = (size_t)blockIdx.x * 128;
    unsigned short* scr = &smem[wave * 2048];

    // ---- stage pair 0 into buf0 FIRST (latency hides under LN) ----
    #pragma unroll
    for (int sub = 0; sub < 4; ++sub) {
        const unsigned short* src = wPack + sub * 2048 + tid * 8;
        unsigned short* dst = &smem[8192 + sub * 2048 + wave * 512];
#if __has_builtin(__builtin_amdgcn_global_load_lds)
        __builtin_amdgcn_global_load_lds(
            (const __attribute__((address_space(1))) void*)src,
            (__attribute__((address_space(3))) void*)dst, 16, 0, 0);
#else
        *(us8*)(dst + lane * 8) = *(const us8*)src;
#endif
    }

    // ---- LN2: 2 passes of 16 rows through wave-private scratch ----
    float4 sc0 = *(const float4*)(ln2s + m16 * 8);
    float4 sc1 = *(const float4*)(ln2s + m16 * 8 + 4);
    float4 bi0 = *(const float4*)(ln2b + m16 * 8);
    float4 bi1 = *(const float4*)(ln2b + m16 * 8 + 4);
    us8 bx[2][4];
    #pragma unroll
    for (int rt = 0; rt < 2; ++rt) {
        #pragma unroll
        for (int it = 0; it < 4; ++it) {
            int lr = it * 4 + g;
            const float* xr = out + (r0 + wave * 32 + rt * 16 + lr) * 128 + m16 * 8;
            float4 v0 = *(const float4*)xr, v1 = *(const float4*)(xr + 4);
            float sum = v0.x + v0.y + v0.z + v0.w + v1.x + v1.y + v1.z + v1.w;
            float sq  = v0.x*v0.x + v0.y*v0.y + v0.z*v0.z + v0.w*v0.w
                      + v1.x*v1.x + v1.y*v1.y + v1.z*v1.z + v1.w*v1.w;
            #pragma unroll
            for (int m = 1; m < 16; m <<= 1) { sum += __shfl_xor(sum, m); sq += __shfl_xor(sq, m); }
            float mu = sum * 0.0078125f;
            float rstd = rsqrtf(sq * 0.0078125f - mu * mu + 1e-6f);
            us8 o;
            o[0] = f2b((v0.x - mu) * rstd * sc0.x + bi0.x);
            o[1] = f2b((v0.y - mu) * rstd * sc0.y + bi0.y);
            o[2] = f2b((v0.z - mu) * rstd * sc0.z + bi0.z);
            o[3] = f2b((v0.w - mu) * rstd * sc0.w + bi0.w);
            o[4] = f2b((v1.x - mu) * rstd * sc1.x + bi1.x);
            o[5] = f2b((v1.y - mu) * rstd * sc1.y + bi1.y);
            o[6] = f2b((v1.z - mu) * rstd * sc1.z + bi1.z);
            o[7] = f2b((v1.w - mu) * rstd * sc1.w + bi1.w);
            lds_st8(scr, lr * 256 + ((m16 * 16) ^ ((lr & 7) << 4)), o);
        }
        // wave-local read-back (lgkm-ordered, no barrier)
        #pragma unroll
        for (int kk = 0; kk < 4; ++kk)
            bx[rt][kk] = lds_ld8(scr, m16 * 256 + ((kk * 64 + g * 16) ^ ((m16 & 7) << 4)));
    }
    __syncthreads();          // pair-0 staging complete + all waves ready

    f32x4 accO[2][8];
    #pragma unroll
    for (int rt = 0; rt < 2; ++rt)
        #pragma unroll
        for (int co = 0; co < 8; ++co) accO[rt][co] = (f32x4){0.f, 0.f, 0.f, 0.f};

    for (int p = 0; p < 16; ++p) {
        if (p < 15) {
            #pragma unroll
            for (int sub = 0; sub < 4; ++sub) {
                const unsigned short* src = wPack + (p + 1) * 8192 + sub * 2048 + tid * 8;
                unsigned short* dst = &smem[8192 + ((p + 1) & 1) * 8192 + sub * 2048 + wave * 512];
#if __has_builtin(__builtin_amdgcn_global_load_lds)
                __builtin_amdgcn_global_load_lds(
                    (const __attribute__((address_space(1))) void*)src,
                    (__attribute__((address_space(3))) void*)dst, 16, 0, 0);
#else
                *(us8*)(dst + lane * 8) = *(const us8*)src;
#endif
            }
        }
        const char* wb = (const char*)&smem[8192 + (p & 1) * 8192];
        // FC1^T half A (aw frags shared across both row-tiles)
        f32x4 hA0 = {0.f,0.f,0.f,0.f}, hA1 = {0.f,0.f,0.f,0.f};
        #pragma unroll
        for (int kk = 0; kk < 4; ++kk) {
            us8 aw = *(const us8*)(wb + kk * 1024 + lane * 16);
            hA0 = mfma16(aw, bx[0][kk], hA0);
            hA1 = mfma16(aw, bx[1][kk], hA1);
        }
        // FC1^T half B
        f32x4 hB0 = {0.f,0.f,0.f,0.f}, hB1 = {0.f,0.f,0.f,0.f};
        #pragma unroll
        for (int kk = 0; kk < 4; ++kk) {
            us8 aw = *(const us8*)(wb + 4096 + kk * 1024 + lane * 16);
            hB0 = mfma16(aw, bx[0][kk], hB0);
            hB1 = mfma16(aw, bx[1][kk], hB1);
        }
        float4 bA = *(const float4*)(fc1B + p * 32 + g * 8);
        float4 bB = *(const float4*)(fc1B + p * 32 + g * 8 + 4);
        us8 pa0, pa1;
        #pragma unroll
        for (int jj = 0; jj < 4; ++jj) {
            float v0 = hA0[jj] + ((const float*)&bA)[jj];
            float z0 = v0 + 0.044715f * v0 * v0 * v0;
            pa0[jj] = f2b(v0 * __builtin_amdgcn_rcpf(1.f + __builtin_amdgcn_exp2f(-2.3022082f * z0)));
            float w0 = hB0[jj] + ((const float*)&bB)[jj];
            float y0 = w0 + 0.044715f * w0 * w0 * w0;
            pa0[4 + jj] = f2b(w0 * __builtin_amdgcn_rcpf(1.f + __builtin_amdgcn_exp2f(-2.3022082f * y0)));
            float v1 = hA1[jj] + ((const float*)&bA)[jj];
            float z1 = v1 + 0.044715f * v1 * v1 * v1;
            pa1[jj] = f2b(v1 * __builtin_amdgcn_rcpf(1.f + __builtin_amdgcn_exp2f(-2.3022082f * z1)));
            float w1 = hB1[jj] + ((const float*)&bB)[jj];
            float y1 = w1 + 0.044715f * w1 * w1 * w1;
            pa1[4 + jj] = f2b(w1 * __builtin_amdgcn_rcpf(1.f + __builtin_amdgcn_exp2f(-2.3022082f * y1)));
        }
        // FC2: 8 K=32 MFMAs per row-tile, bw frag shared across tiles
        #pragma unroll
        for (int co = 0; co < 8; ++co) {
            us8 bw = *(const us8*)(wb + 8192 + co * 1024 + lane * 16);
            accO[0][co] = mfma16(pa0, bw, accO[0][co]);
            accO[1][co] = mfma16(pa1, bw, accO[1][co]);
        }
        __syncthreads();
    }

    // ---- epilogue: bias + residual, in-place fp32 ----
    #pragma unroll
    for (int rt = 0; rt < 2; ++rt)
        #pragma unroll
        for (int co = 0; co < 8; ++co) {
            int col = co * 16 + m16;
            float b2v = fc2B[col];
            #pragma unroll
            for (int jj = 0; jj < 4; ++jj) {
                size_t row = r0 + wave * 32 + rt * 16 + g * 4 + jj;
                float* op = out + row * 128 + col;
                *op = accO[rt][co][jj] + b2v + *op;
            }
        }
}

// ---------- launch ----------
extern "C" void kernel_launch(void* const* d_in, const int* in_sizes, int n_in,
                              void* d_out, int out_size, void* d_ws, size_t ws_size,
                              hipStream_t stream) {
    const float* x        = (const float*)d_in[0];
    const float* ln1_s    = (const float*)d_in[1];
    const float* ln1_b    = (const float*)d_in[2];
    const float* qkv_w    = (const float*)d_in[3];
    const float* qkv_b    = (const float*)d_in[4];
    const float* rel_bias = (const float*)d_in[5];
    const float* proj_w   = (const float*)d_in[6];
    const float* proj_b   = (const float*)d_in[7];
    const float* ln2_s    = (const float*)d_in[8];
    const float* ln2_b    = (const float*)d_in[9];
    const float* fc1_w    = (const float*)d_in[10];
    const float* fc1_b    = (const float*)d_in[11];
    const float* fc2_w    = (const float*)d_in[12];
    const float* fc2_b    = (const float*)d_in[13];
    float* out = (float*)d_out;
    char* ws = (char*)d_ws;

    unsigned short* qkv_wp  = (unsigned short*)(ws);             // 96KB packed qkv frags
    unsigned short* proj_wp = (unsigned short*)(ws + 98304);     // 32KB packed proj frags
    unsigned short* wpack   = (unsigned short*)(ws + 131072);    // 256KB packed MLP (16x16KB)
    float*          qkv_bs  = (float*)(ws + 393216);             // 1.5KB scaled qkv bias

    k_pack_qkvw<<<192, 256, 0, stream>>>(qkv_w, qkv_wp);
    k_scale_qkvb<<<2, 256, 0, stream>>>(qkv_b, qkv_bs);
    k_pack_projw<<<64, 256, 0, stream>>>(proj_w, proj_wp);
    k_pack_mlp<<<512, 256, 0, stream>>>(fc1_w, fc2_w, wpack);

    k_block1<<<4096, 256, 0, stream>>>(x, ln1_s, ln1_b, qkv_wp, qkv_bs, rel_bias,
                                       proj_wp, proj_b, out);
    k_block2<<<2048, 256, 0, stream>>>(out, ln2_s, ln2_b, wpack, fc1_b, fc2_b);
}